// Round 2
// baseline (1163.702 us; speedup 1.0000x reference)
//
#include <hip/hip_runtime.h>
#include <math.h>

#define HH 50     // hidden features
#define HS 64     // padded row stride (floats) -> 256B rows, float4 aligned

// ---------------- degree / CSR build ----------------
__global__ void deg_kernel(const int* __restrict__ ei, int E, int* __restrict__ cnt) {
    int e = blockIdx.x * 256 + threadIdx.x;
    if (e < E) {
        int d = ei[(size_t)E + e];
        atomicAdd(&cnt[d], 1);
    }
}

__global__ void dinv_kernel(const int* __restrict__ cnt, float* __restrict__ dinv, int N) {
    int i = blockIdx.x * 256 + threadIdx.x;
    if (i < N) dinv[i] = 1.0f / sqrtf((float)(cnt[i] + 1)); // +1 self loop
}

__global__ void scan_kernel(const int* __restrict__ cnt, int* __restrict__ rowptr, int N) {
    __shared__ int part[1024];
    int t = threadIdx.x;
    int chunk = (N + 1023) >> 10;
    int beg = t * chunk; if (beg > N) beg = N;
    int end = beg + chunk; if (end > N) end = N;
    int s = 0;
    for (int i = beg; i < end; i++) s += cnt[i];
    part[t] = s;
    __syncthreads();
    for (int off = 1; off < 1024; off <<= 1) {
        int v = (t >= off) ? part[t - off] : 0;
        __syncthreads();
        part[t] += v;
        __syncthreads();
    }
    int run = (t == 0) ? 0 : part[t - 1];
    for (int i = beg; i < end; i++) { rowptr[i] = run; run += cnt[i]; }
    if (t == 1023) rowptr[N] = run;
}

__global__ void fill_kernel(const int* __restrict__ ei, int E,
                            const int* __restrict__ rowptr, int* __restrict__ cnt,
                            int* __restrict__ colidx) {
    int e = blockIdx.x * 256 + threadIdx.x;
    if (e < E) {
        int s = ei[e];
        int d = ei[(size_t)E + e];
        int pos = rowptr[d] + atomicAdd(&cnt[d], 1);
        colidx[pos] = s;
    }
}

// ---------------- GEMM: out[row][c] = dinv[row] * sum_k in[row][k]*W[k][c] ----------------
// W staged in LDS padded to [KP][52]; each thread computes one full row (52 accs).
__global__ void gemm_kernel(const float* __restrict__ in, int in_f4_stride, int k4,
                            const float* __restrict__ W, int K, int H,
                            const float* __restrict__ dinv, float* __restrict__ out, int N) {
    __shared__ float4 Wl[136 * 13];   // max KP=136, 52 floats per row
    int KP = k4 * 4;
    for (int idx = threadIdx.x; idx < KP * 52; idx += blockDim.x) {
        int r = idx / 52, c = idx % 52;
        ((float*)Wl)[idx] = (r < K && c < H) ? W[r * H + c] : 0.0f;
    }
    __syncthreads();
    int row = blockIdx.x * blockDim.x + threadIdx.x;
    if (row >= N) return;
    float4 acc[13];
#pragma unroll
    for (int i = 0; i < 13; i++) acc[i] = make_float4(0.f, 0.f, 0.f, 0.f);
    const float4* inr = (const float4*)in + (size_t)row * in_f4_stride;
    for (int kk = 0; kk < k4; kk++) {
        float4 xv = inr[kk];
        float xs0 = xv.x, xs1 = xv.y, xs2 = xv.z, xs3 = xv.w;
        const float4* w0 = &Wl[(kk * 4 + 0) * 13];
        const float4* w1 = &Wl[(kk * 4 + 1) * 13];
        const float4* w2 = &Wl[(kk * 4 + 2) * 13];
        const float4* w3 = &Wl[(kk * 4 + 3) * 13];
#pragma unroll
        for (int c = 0; c < 13; c++) {
            float4 a = acc[c];
            float4 wa = w0[c];
            a.x += xs0 * wa.x; a.y += xs0 * wa.y; a.z += xs0 * wa.z; a.w += xs0 * wa.w;
            float4 wb = w1[c];
            a.x += xs1 * wb.x; a.y += xs1 * wb.y; a.z += xs1 * wb.z; a.w += xs1 * wb.w;
            float4 wc = w2[c];
            a.x += xs2 * wc.x; a.y += xs2 * wc.y; a.z += xs2 * wc.z; a.w += xs2 * wc.w;
            float4 wd = w3[c];
            a.x += xs3 * wd.x; a.y += xs3 * wd.y; a.z += xs3 * wd.z; a.w += xs3 * wd.w;
            acc[c] = a;
        }
    }
    float dv = dinv[row];
    float4* outr = (float4*)out + (size_t)row * (HS / 4);
#pragma unroll
    for (int c = 0; c < 13; c++) {
        float4 v = acc[c];
        v.x *= dv; v.y *= dv; v.z *= dv; v.w *= dv;
        outr[c] = v;
    }
    float4 z = make_float4(0.f, 0.f, 0.f, 0.f);
    outr[13] = z; outr[14] = z; outr[15] = z;
}

// ---------------- aggregation: out[i] = relu(dinv[i]*(hs[i] + sum_nb hs[s]) + b) ----------------
// thread t -> node t>>4, float4 chunk t&15 (rows are 16 float4 = 64 floats)
__global__ void agg_kernel(const float* __restrict__ hs, const int* __restrict__ rowptr,
                           const int* __restrict__ colidx, const float* __restrict__ dinv,
                           const float* __restrict__ bias, float* __restrict__ out, int N) {
    int t = blockIdx.x * blockDim.x + threadIdx.x;
    int node = t >> 4;
    int q = t & 15;
    if (node >= N) return;
    const float4* base = (const float4*)hs;
    float4 acc = base[(size_t)node * 16 + q];   // self loop term
    int beg = rowptr[node], end = rowptr[node + 1];
    for (int e = beg; e < end; e++) {
        int s = colidx[e];
        float4 v = base[(size_t)s * 16 + q];
        acc.x += v.x; acc.y += v.y; acc.z += v.z; acc.w += v.w;
    }
    float dv = dinv[node];
    int c0 = q * 4;
    float b0 = (c0 + 0 < HH) ? bias[c0 + 0] : 0.0f;
    float b1 = (c0 + 1 < HH) ? bias[c0 + 1] : 0.0f;
    float b2 = (c0 + 2 < HH) ? bias[c0 + 2] : 0.0f;
    float b3 = (c0 + 3 < HH) ? bias[c0 + 3] : 0.0f;
    float4 r;
    r.x = fmaxf(acc.x * dv + b0, 0.0f);
    r.y = fmaxf(acc.y * dv + b1, 0.0f);
    r.z = fmaxf(acc.z * dv + b2, 0.0f);
    r.w = fmaxf(acc.w * dv + b3, 0.0f);
    if (c0 >= HH) r = make_float4(0.f, 0.f, 0.f, 0.f);  // pure-pad chunks stay exactly 0
    ((float4*)out)[(size_t)node * 16 + q] = r;
}

// ---------------- pooling ----------------
__global__ void pool_kernel(const float* __restrict__ h, const int* __restrict__ batch,
                            float* __restrict__ gsum, float* __restrict__ gcnt, int N) {
    int t = blockIdx.x * blockDim.x + threadIdx.x;
    int node = t >> 4, q = t & 15;
    if (node >= N) return;
    int b = batch[node];
    if (q < 13) {   // chunks covering c<52 (50,51 are zeros)
        float4 v = ((const float4*)h)[(size_t)node * 16 + q];
        int c0 = q * 4;
        atomicAdd(&gsum[b * HS + c0 + 0], v.x);
        atomicAdd(&gsum[b * HS + c0 + 1], v.y);
        atomicAdd(&gsum[b * HS + c0 + 2], v.z);
        atomicAdd(&gsum[b * HS + c0 + 3], v.w);
    }
    if (q == 0) atomicAdd(&gcnt[b], 1.0f);
}

__global__ void final_kernel(const float* __restrict__ gsum, const float* __restrict__ gcnt,
                             const float* __restrict__ Wl, const float* __restrict__ bl,
                             float* __restrict__ out, int G) {
    int b = blockIdx.x * blockDim.x + threadIdx.x;
    if (b >= G) return;
    float inv = 1.0f / fmaxf(gcnt[b], 1.0f);
    float acc = 0.0f;
    for (int c = 0; c < HH; c++) acc += gsum[b * HS + c] * Wl[c];
    float x = acc * inv + bl[0];
    out[b] = 1.0f / (1.0f + expf(-x));
}

extern "C" void kernel_launch(void* const* d_in, const int* in_sizes, int n_in,
                              void* d_out, int out_size, void* d_ws, size_t ws_size,
                              hipStream_t stream) {
    const float* x     = (const float*)d_in[0];
    const int*   ei    = (const int*)d_in[1];      // harness converts int64 -> int32
    const int*   batch = (const int*)d_in[2];      // harness converts int64 -> int32
    const float* W1    = (const float*)d_in[3];
    const float* b1    = (const float*)d_in[4];
    const float* W2    = (const float*)d_in[5];
    const float* b2    = (const float*)d_in[6];
    const float* Wl    = (const float*)d_in[7];
    const float* bl    = (const float*)d_in[8];
    float* out = (float*)d_out;

    int N = in_sizes[2];
    int E = in_sizes[1] / 2;
    int F = in_sizes[0] / N;       // 136
    int G = out_size;              // 256 graphs

    char* ws = (char*)d_ws;
    size_t off = 0;
    auto alloc = [&](size_t bytes) -> void* {
        void* p = ws + off;
        off += (bytes + 255) & ~(size_t)255;
        return p;
    };
    int*   cnt    = (int*)alloc((size_t)N * 4);
    float* dinv   = (float*)alloc((size_t)N * 4);
    int*   rowptr = (int*)alloc((size_t)(N + 1) * 4);
    int*   colidx = (int*)alloc((size_t)E * 4);
    float* hs     = (float*)alloc((size_t)N * HS * 4);
    float* buf    = (float*)alloc((size_t)N * HS * 4);
    float* gsum   = (float*)alloc((size_t)G * HS * 4);
    float* gcnt   = (float*)alloc((size_t)G * 4);

    // CSR build (by dst)
    hipMemsetAsync(cnt, 0, (size_t)N * 4, stream);
    deg_kernel<<<(E + 255) / 256, 256, 0, stream>>>(ei, E, cnt);
    dinv_kernel<<<(N + 255) / 256, 256, 0, stream>>>(cnt, dinv, N);
    scan_kernel<<<1, 1024, 0, stream>>>(cnt, rowptr, N);
    hipMemsetAsync(cnt, 0, (size_t)N * 4, stream);
    fill_kernel<<<(E + 255) / 256, 256, 0, stream>>>(ei, E, rowptr, cnt, colidx);

    int aggBlocks = ((N * 16) + 255) / 256;

    // layer 1
    gemm_kernel<<<(N + 255) / 256, 256, 0, stream>>>(x, F / 4, F / 4, W1, F, HH, dinv, hs, N);
    agg_kernel<<<aggBlocks, 256, 0, stream>>>(hs, rowptr, colidx, dinv, b1, buf, N);

    // layer 2 (input rows padded to HS with zeros -> read 13 float4 = 52 floats)
    gemm_kernel<<<(N + 255) / 256, 256, 0, stream>>>(buf, HS / 4, 13, W2, HH, HH, dinv, hs, N);
    agg_kernel<<<aggBlocks, 256, 0, stream>>>(hs, rowptr, colidx, dinv, b2, buf, N);

    // pooling + head
    hipMemsetAsync(gsum, 0, (size_t)G * HS * 4, stream);
    hipMemsetAsync(gcnt, 0, (size_t)G * 4, stream);
    pool_kernel<<<aggBlocks, 256, 0, stream>>>(buf, batch, gsum, gcnt, N);
    final_kernel<<<1, 256, 0, stream>>>(gsum, gcnt, Wl, bl, out, G);
}

// Round 3
// 855.195 us; speedup vs baseline: 1.3607x; 1.3607x over previous
//
#include <hip/hip_runtime.h>
#include <math.h>

#define HH 50     // hidden features
#define HS 64     // padded row stride (floats) -> 256B rows, float4 aligned

// ---------------- degree / CSR build ----------------
__global__ void deg_kernel(const int* __restrict__ ei, int E, int* __restrict__ cnt) {
    int e = blockIdx.x * 256 + threadIdx.x;
    if (e < E) {
        int d = ei[(size_t)E + e];
        atomicAdd(&cnt[d], 1);
    }
}

__global__ void dinv_kernel(const int* __restrict__ cnt, float* __restrict__ dinv, int N) {
    int i = blockIdx.x * 256 + threadIdx.x;
    if (i < N) dinv[i] = 1.0f / sqrtf((float)(cnt[i] + 1)); // +1 self loop
}

__global__ void scan_kernel(const int* __restrict__ cnt, int* __restrict__ rowptr, int N) {
    __shared__ int part[1024];
    int t = threadIdx.x;
    int chunk = (N + 1023) >> 10;
    int beg = t * chunk; if (beg > N) beg = N;
    int end = beg + chunk; if (end > N) end = N;
    int s = 0;
    for (int i = beg; i < end; i++) s += cnt[i];
    part[t] = s;
    __syncthreads();
    for (int off = 1; off < 1024; off <<= 1) {
        int v = (t >= off) ? part[t - off] : 0;
        __syncthreads();
        part[t] += v;
        __syncthreads();
    }
    int run = (t == 0) ? 0 : part[t - 1];
    for (int i = beg; i < end; i++) { rowptr[i] = run; run += cnt[i]; }
    if (t == 1023) rowptr[N] = run;
}

__global__ void fill_kernel(const int* __restrict__ ei, int E,
                            const int* __restrict__ rowptr, int* __restrict__ cnt,
                            int* __restrict__ colidx) {
    int e = blockIdx.x * 256 + threadIdx.x;
    if (e < E) {
        int s = ei[e];
        int d = ei[(size_t)E + e];
        int pos = rowptr[d] + atomicAdd(&cnt[d], 1);
        colidx[pos] = s;
    }
}

// ---------------- graph boundaries (batch is sorted) ----------------
__global__ void gbounds_kernel(const int* __restrict__ batch, int N, int G,
                               int* __restrict__ gptr) {
    int b = blockIdx.x * blockDim.x + threadIdx.x;
    if (b > G) return;
    // first index i with batch[i] >= b
    int lo = 0, hi = N;
    while (lo < hi) {
        int mid = (lo + hi) >> 1;
        if (batch[mid] < b) lo = mid + 1; else hi = mid;
    }
    gptr[b] = lo;
}

// ---------------- GEMM: out[row][c] = dinv[row] * sum_k in[row][k]*W[k][c] ----------------
__global__ void gemm_kernel(const float* __restrict__ in, int in_f4_stride, int k4,
                            const float* __restrict__ W, int K, int H,
                            const float* __restrict__ dinv, float* __restrict__ out, int N) {
    __shared__ float4 Wl[136 * 13];   // max KP=136, 52 floats per row
    int KP = k4 * 4;
    for (int idx = threadIdx.x; idx < KP * 52; idx += blockDim.x) {
        int r = idx / 52, c = idx % 52;
        ((float*)Wl)[idx] = (r < K && c < H) ? W[r * H + c] : 0.0f;
    }
    __syncthreads();
    int row = blockIdx.x * blockDim.x + threadIdx.x;
    if (row >= N) return;
    float4 acc[13];
#pragma unroll
    for (int i = 0; i < 13; i++) acc[i] = make_float4(0.f, 0.f, 0.f, 0.f);
    const float4* inr = (const float4*)in + (size_t)row * in_f4_stride;
    for (int kk = 0; kk < k4; kk++) {
        float4 xv = inr[kk];
        float xs0 = xv.x, xs1 = xv.y, xs2 = xv.z, xs3 = xv.w;
        const float4* w0 = &Wl[(kk * 4 + 0) * 13];
        const float4* w1 = &Wl[(kk * 4 + 1) * 13];
        const float4* w2 = &Wl[(kk * 4 + 2) * 13];
        const float4* w3 = &Wl[(kk * 4 + 3) * 13];
#pragma unroll
        for (int c = 0; c < 13; c++) {
            float4 a = acc[c];
            float4 wa = w0[c];
            a.x += xs0 * wa.x; a.y += xs0 * wa.y; a.z += xs0 * wa.z; a.w += xs0 * wa.w;
            float4 wb = w1[c];
            a.x += xs1 * wb.x; a.y += xs1 * wb.y; a.z += xs1 * wb.z; a.w += xs1 * wb.w;
            float4 wc = w2[c];
            a.x += xs2 * wc.x; a.y += xs2 * wc.y; a.z += xs2 * wc.z; a.w += xs2 * wc.w;
            float4 wd = w3[c];
            a.x += xs3 * wd.x; a.y += xs3 * wd.y; a.z += xs3 * wd.z; a.w += xs3 * wd.w;
            acc[c] = a;
        }
    }
    float dv = dinv[row];
    float4* outr = (float4*)out + (size_t)row * (HS / 4);
#pragma unroll
    for (int c = 0; c < 13; c++) {
        float4 v = acc[c];
        v.x *= dv; v.y *= dv; v.z *= dv; v.w *= dv;
        outr[c] = v;
    }
    float4 z = make_float4(0.f, 0.f, 0.f, 0.f);
    outr[13] = z; outr[14] = z; outr[15] = z;
}

// ---------------- aggregation: out[i] = relu(dinv[i]*(hs[i] + sum_nb hs[s]) + b) ----------------
__global__ void agg_kernel(const float* __restrict__ hs, const int* __restrict__ rowptr,
                           const int* __restrict__ colidx, const float* __restrict__ dinv,
                           const float* __restrict__ bias, float* __restrict__ out, int N) {
    int t = blockIdx.x * blockDim.x + threadIdx.x;
    int node = t >> 4;
    int q = t & 15;
    if (node >= N) return;
    const float4* base = (const float4*)hs;
    float4 acc = base[(size_t)node * 16 + q];   // self loop term
    int beg = rowptr[node], end = rowptr[node + 1];
    for (int e = beg; e < end; e++) {
        int s = colidx[e];
        float4 v = base[(size_t)s * 16 + q];
        acc.x += v.x; acc.y += v.y; acc.z += v.z; acc.w += v.w;
    }
    float dv = dinv[node];
    int c0 = q * 4;
    float b0 = (c0 + 0 < HH) ? bias[c0 + 0] : 0.0f;
    float b1 = (c0 + 1 < HH) ? bias[c0 + 1] : 0.0f;
    float b2 = (c0 + 2 < HH) ? bias[c0 + 2] : 0.0f;
    float b3 = (c0 + 3 < HH) ? bias[c0 + 3] : 0.0f;
    float4 r;
    r.x = fmaxf(acc.x * dv + b0, 0.0f);
    r.y = fmaxf(acc.y * dv + b1, 0.0f);
    r.z = fmaxf(acc.z * dv + b2, 0.0f);
    r.w = fmaxf(acc.w * dv + b3, 0.0f);
    if (c0 >= HH) r = make_float4(0.f, 0.f, 0.f, 0.f);  // pure-pad chunks stay exactly 0
    ((float4*)out)[(size_t)node * 16 + q] = r;
}

// ---------------- pooling + head, one block per graph, no atomics ----------------
// 256 threads = 16 node-lanes (sub) x 16 float4-chunks (q).
__global__ void pool_head_kernel(const float* __restrict__ h, const int* __restrict__ gptr,
                                 const float* __restrict__ Wl, const float* __restrict__ bl,
                                 float* __restrict__ out, int G) {
    __shared__ float4 red[16][16];    // [sub][q]
    int b = blockIdx.x;
    int t = threadIdx.x;
    int sub = t >> 4, q = t & 15;
    int beg = gptr[b], end = gptr[b + 1];
    const float4* base = (const float4*)h;
    float4 acc = make_float4(0.f, 0.f, 0.f, 0.f);
    for (int node = beg + sub; node < end; node += 16) {
        float4 v = base[(size_t)node * 16 + q];
        acc.x += v.x; acc.y += v.y; acc.z += v.z; acc.w += v.w;
    }
    red[sub][q] = acc;
    __syncthreads();
#pragma unroll
    for (int off = 8; off >= 1; off >>= 1) {
        if (sub < off) {
            float4 a = red[sub][q], c = red[sub + off][q];
            a.x += c.x; a.y += c.y; a.z += c.z; a.w += c.w;
            red[sub][q] = a;
        }
        __syncthreads();
    }
    if (t == 0) {
        const float* g = (const float*)&red[0][0];   // 64 floats, chunk q at [q*4]
        float dot = 0.0f;
        for (int c = 0; c < HH; c++) dot += g[c] * Wl[c];
        float cnt = (float)(end - beg);
        float x = dot / fmaxf(cnt, 1.0f) + bl[0];
        out[b] = 1.0f / (1.0f + expf(-x));
    }
}

extern "C" void kernel_launch(void* const* d_in, const int* in_sizes, int n_in,
                              void* d_out, int out_size, void* d_ws, size_t ws_size,
                              hipStream_t stream) {
    const float* x     = (const float*)d_in[0];
    const int*   ei    = (const int*)d_in[1];      // harness converts int64 -> int32
    const int*   batch = (const int*)d_in[2];      // harness converts int64 -> int32
    const float* W1    = (const float*)d_in[3];
    const float* b1    = (const float*)d_in[4];
    const float* W2    = (const float*)d_in[5];
    const float* b2    = (const float*)d_in[6];
    const float* Wl    = (const float*)d_in[7];
    const float* bl    = (const float*)d_in[8];
    float* out = (float*)d_out;

    int N = in_sizes[2];
    int E = in_sizes[1] / 2;
    int F = in_sizes[0] / N;       // 136
    int G = out_size;              // 256 graphs

    char* ws = (char*)d_ws;
    size_t off = 0;
    auto alloc = [&](size_t bytes) -> void* {
        void* p = ws + off;
        off += (bytes + 255) & ~(size_t)255;
        return p;
    };
    int*   cnt    = (int*)alloc((size_t)N * 4);
    float* dinv   = (float*)alloc((size_t)N * 4);
    int*   rowptr = (int*)alloc((size_t)(N + 1) * 4);
    int*   colidx = (int*)alloc((size_t)E * 4);
    float* hs     = (float*)alloc((size_t)N * HS * 4);
    float* buf    = (float*)alloc((size_t)N * HS * 4);
    int*   gptr   = (int*)alloc((size_t)(G + 1) * 4);

    // CSR build (by dst)
    hipMemsetAsync(cnt, 0, (size_t)N * 4, stream);
    deg_kernel<<<(E + 255) / 256, 256, 0, stream>>>(ei, E, cnt);
    dinv_kernel<<<(N + 255) / 256, 256, 0, stream>>>(cnt, dinv, N);
    scan_kernel<<<1, 1024, 0, stream>>>(cnt, rowptr, N);
    hipMemsetAsync(cnt, 0, (size_t)N * 4, stream);
    fill_kernel<<<(E + 255) / 256, 256, 0, stream>>>(ei, E, rowptr, cnt, colidx);
    gbounds_kernel<<<2, 256, 0, stream>>>(batch, N, G, gptr);

    int aggBlocks = ((N * 16) + 255) / 256;

    // layer 1
    gemm_kernel<<<(N + 255) / 256, 256, 0, stream>>>(x, F / 4, F / 4, W1, F, HH, dinv, hs, N);
    agg_kernel<<<aggBlocks, 256, 0, stream>>>(hs, rowptr, colidx, dinv, b1, buf, N);

    // layer 2 (input rows padded to HS with zeros -> read 13 float4 = 52 floats)
    gemm_kernel<<<(N + 255) / 256, 256, 0, stream>>>(buf, HS / 4, 13, W2, HH, HH, dinv, hs, N);
    agg_kernel<<<aggBlocks, 256, 0, stream>>>(hs, rowptr, colidx, dinv, b2, buf, N);

    // pooling + fused head
    pool_head_kernel<<<G, 256, 0, stream>>>(buf, gptr, Wl, bl, out, G);
}

// Round 4
// 504.725 us; speedup vs baseline: 2.3056x; 1.6944x over previous
//
#include <hip/hip_runtime.h>
#include <math.h>

#define HH 50     // hidden features
#define HS 64     // padded row stride (floats) -> 256B rows, float4 aligned
#define BSH 9     // bucket shift: 512 nodes per bucket
#define BSZ 512
#define CH 16384  // edges per chunk in bucketed CSR build

// ---------------- bucketed CSR build (no global atomics) ----------------
// Pass A: per-chunk histogram of dst buckets.
__global__ void histA_kernel(const int* __restrict__ ei, int E, int NB, int NC,
                             int* __restrict__ blockHist) {
    __shared__ int hist[256];
    int c = blockIdx.x;
    int tid = threadIdx.x;
    hist[tid] = 0;
    __syncthreads();
    int beg = c * CH, end = min(E, beg + CH);
    for (int i = beg + tid; i < end; i += 256) {
        int d = ei[(size_t)E + i];
        atomicAdd(&hist[d >> BSH], 1);
    }
    __syncthreads();
    if (tid < NB) blockHist[tid * NC + c] = hist[tid];   // bucket-major
}

// Pass B0: exclusive scan of blockHist (bucket-major) -> scanned; rowptr[N] = E.
__global__ void scanB_kernel(const int* __restrict__ blockHist, int M,
                             int* __restrict__ scanned, int* __restrict__ rowptr,
                             int N, int E) {
    __shared__ int part[1024];
    int t = threadIdx.x;
    int chunk = (M + 1023) >> 10;
    int beg = t * chunk; if (beg > M) beg = M;
    int end = beg + chunk; if (end > M) end = M;
    int s = 0;
    for (int i = beg; i < end; i++) s += blockHist[i];
    part[t] = s;
    __syncthreads();
    for (int off = 1; off < 1024; off <<= 1) {
        int v = (t >= off) ? part[t - off] : 0;
        __syncthreads();
        part[t] += v;
        __syncthreads();
    }
    int run = (t == 0) ? 0 : part[t - 1];
    for (int i = beg; i < end; i++) { scanned[i] = run; run += blockHist[i]; }
    if (t == 0) rowptr[N] = E;
}

// Pass B1: scatter edges into bucket-contiguous ebuf, packed (dstLow<<17)|src.
__global__ void scatterB_kernel(const int* __restrict__ ei, int E, int NB, int NC,
                                const int* __restrict__ scanned, int* __restrict__ ebuf) {
    __shared__ int offs[256];
    int c = blockIdx.x;
    int tid = threadIdx.x;
    if (tid < NB) offs[tid] = scanned[tid * NC + c];
    __syncthreads();
    int beg = c * CH, end = min(E, beg + CH);
    for (int i = beg + tid; i < end; i += 256) {
        int s = ei[i];
        int d = ei[(size_t)E + i];
        int b = d >> BSH;
        int pos = atomicAdd(&offs[b], 1);
        ebuf[pos] = ((d & (BSZ - 1)) << 17) | s;
    }
}

// Pass C: per-bucket fine CSR: count -> scan -> rowptr/dinv -> place srcs.
__global__ void buildC_kernel(const int* __restrict__ ebuf, const int* __restrict__ scanned,
                              int NB, int NC, int N, int E,
                              int* __restrict__ rowptr, float* __restrict__ dinv,
                              int* __restrict__ colidx) {
    __shared__ int cnt[BSZ], loc[BSZ], woff[BSZ], part[256];
    int b = blockIdx.x;
    int tid = threadIdx.x;
    int ebeg = scanned[b * NC];
    int eend = (b == NB - 1) ? E : scanned[(b + 1) * NC];
    cnt[tid] = 0; cnt[tid + 256] = 0;
    __syncthreads();
    for (int i = ebeg + tid; i < eend; i += 256) {
        int dl = ebuf[i] >> 17;
        atomicAdd(&cnt[dl], 1);
    }
    __syncthreads();
    int a0 = cnt[2 * tid], a1 = cnt[2 * tid + 1];
    part[tid] = a0 + a1;
    __syncthreads();
    for (int off = 1; off < 256; off <<= 1) {
        int v = (tid >= off) ? part[tid - off] : 0;
        __syncthreads();
        part[tid] += v;
        __syncthreads();
    }
    int base = (tid == 0) ? 0 : part[tid - 1];
    loc[2 * tid] = base;
    loc[2 * tid + 1] = base + a0;
    woff[2 * tid] = base;
    woff[2 * tid + 1] = base + a0;
    __syncthreads();
    for (int dl = tid; dl < BSZ; dl += 256) {
        int node = (b << BSH) + dl;
        if (node < N) {
            rowptr[node] = ebeg + loc[dl];
            dinv[node] = 1.0f / sqrtf((float)(cnt[dl] + 1));   // +1 self loop
        }
    }
    __syncthreads();
    for (int i = ebeg + tid; i < eend; i += 256) {
        int p = ebuf[i];
        int dl = p >> 17;
        int s = p & 0x1FFFF;
        int pos = atomicAdd(&woff[dl], 1);
        colidx[ebeg + pos] = s;
    }
}

// ---------------- graph boundaries (batch is sorted) ----------------
__global__ void gbounds_kernel(const int* __restrict__ batch, int N, int G,
                               int* __restrict__ gptr) {
    int b = blockIdx.x * blockDim.x + threadIdx.x;
    if (b > G) return;
    int lo = 0, hi = N;
    while (lo < hi) {
        int mid = (lo + hi) >> 1;
        if (batch[mid] < b) lo = mid + 1; else hi = mid;
    }
    gptr[b] = lo;
}

// ---------------- GEMM: out[row][c] = dinv[row] * sum_k in[row][k]*W[k][c] ----------------
__global__ void gemm_kernel(const float* __restrict__ in, int in_f4_stride, int k4,
                            const float* __restrict__ W, int K, int H,
                            const float* __restrict__ dinv, float* __restrict__ out, int N) {
    __shared__ float4 Wl[136 * 13];   // max KP=136, 52 floats per row
    int KP = k4 * 4;
    for (int idx = threadIdx.x; idx < KP * 52; idx += blockDim.x) {
        int r = idx / 52, c = idx % 52;
        ((float*)Wl)[idx] = (r < K && c < H) ? W[r * H + c] : 0.0f;
    }
    __syncthreads();
    int row = blockIdx.x * blockDim.x + threadIdx.x;
    if (row >= N) return;
    float4 acc[13];
#pragma unroll
    for (int i = 0; i < 13; i++) acc[i] = make_float4(0.f, 0.f, 0.f, 0.f);
    const float4* inr = (const float4*)in + (size_t)row * in_f4_stride;
    for (int kk = 0; kk < k4; kk++) {
        float4 xv = inr[kk];
        float xs0 = xv.x, xs1 = xv.y, xs2 = xv.z, xs3 = xv.w;
        const float4* w0 = &Wl[(kk * 4 + 0) * 13];
        const float4* w1 = &Wl[(kk * 4 + 1) * 13];
        const float4* w2 = &Wl[(kk * 4 + 2) * 13];
        const float4* w3 = &Wl[(kk * 4 + 3) * 13];
#pragma unroll
        for (int c = 0; c < 13; c++) {
            float4 a = acc[c];
            float4 wa = w0[c];
            a.x += xs0 * wa.x; a.y += xs0 * wa.y; a.z += xs0 * wa.z; a.w += xs0 * wa.w;
            float4 wb = w1[c];
            a.x += xs1 * wb.x; a.y += xs1 * wb.y; a.z += xs1 * wb.z; a.w += xs1 * wb.w;
            float4 wc = w2[c];
            a.x += xs2 * wc.x; a.y += xs2 * wc.y; a.z += xs2 * wc.z; a.w += xs2 * wc.w;
            float4 wd = w3[c];
            a.x += xs3 * wd.x; a.y += xs3 * wd.y; a.z += xs3 * wd.z; a.w += xs3 * wd.w;
            acc[c] = a;
        }
    }
    float dv = dinv[row];
    float4* outr = (float4*)out + (size_t)row * (HS / 4);
#pragma unroll
    for (int c = 0; c < 13; c++) {
        float4 v = acc[c];
        v.x *= dv; v.y *= dv; v.z *= dv; v.w *= dv;
        outr[c] = v;
    }
    float4 z = make_float4(0.f, 0.f, 0.f, 0.f);
    outr[13] = z; outr[14] = z; outr[15] = z;
}

// ---------------- aggregation: out[i] = relu(dinv[i]*(hs[i] + sum_nb hs[s]) + b) ----------------
__global__ void agg_kernel(const float* __restrict__ hs, const int* __restrict__ rowptr,
                           const int* __restrict__ colidx, const float* __restrict__ dinv,
                           const float* __restrict__ bias, float* __restrict__ out, int N) {
    int t = blockIdx.x * blockDim.x + threadIdx.x;
    int node = t >> 4;
    int q = t & 15;
    if (node >= N) return;
    const float4* base = (const float4*)hs;
    float4 acc = base[(size_t)node * 16 + q];   // self loop term
    int beg = rowptr[node], end = rowptr[node + 1];
    for (int e = beg; e < end; e++) {
        int s = colidx[e];
        float4 v = base[(size_t)s * 16 + q];
        acc.x += v.x; acc.y += v.y; acc.z += v.z; acc.w += v.w;
    }
    float dv = dinv[node];
    int c0 = q * 4;
    float b0 = (c0 + 0 < HH) ? bias[c0 + 0] : 0.0f;
    float b1 = (c0 + 1 < HH) ? bias[c0 + 1] : 0.0f;
    float b2 = (c0 + 2 < HH) ? bias[c0 + 2] : 0.0f;
    float b3 = (c0 + 3 < HH) ? bias[c0 + 3] : 0.0f;
    float4 r;
    r.x = fmaxf(acc.x * dv + b0, 0.0f);
    r.y = fmaxf(acc.y * dv + b1, 0.0f);
    r.z = fmaxf(acc.z * dv + b2, 0.0f);
    r.w = fmaxf(acc.w * dv + b3, 0.0f);
    if (c0 >= HH) r = make_float4(0.f, 0.f, 0.f, 0.f);  // pure-pad chunks stay exactly 0
    ((float4*)out)[(size_t)node * 16 + q] = r;
}

// ---------------- pooling + head, one block per graph, no atomics ----------------
__global__ void pool_head_kernel(const float* __restrict__ h, const int* __restrict__ gptr,
                                 const float* __restrict__ Wl, const float* __restrict__ bl,
                                 float* __restrict__ out, int G) {
    __shared__ float4 red[16][16];    // [sub][q]
    int b = blockIdx.x;
    int t = threadIdx.x;
    int sub = t >> 4, q = t & 15;
    int beg = gptr[b], end = gptr[b + 1];
    const float4* base = (const float4*)h;
    float4 acc = make_float4(0.f, 0.f, 0.f, 0.f);
    for (int node = beg + sub; node < end; node += 16) {
        float4 v = base[(size_t)node * 16 + q];
        acc.x += v.x; acc.y += v.y; acc.z += v.z; acc.w += v.w;
    }
    red[sub][q] = acc;
    __syncthreads();
#pragma unroll
    for (int off = 8; off >= 1; off >>= 1) {
        if (sub < off) {
            float4 a = red[sub][q], c = red[sub + off][q];
            a.x += c.x; a.y += c.y; a.z += c.z; a.w += c.w;
            red[sub][q] = a;
        }
        __syncthreads();
    }
    if (t == 0) {
        const float* g = (const float*)&red[0][0];
        float dot = 0.0f;
        for (int c = 0; c < HH; c++) dot += g[c] * Wl[c];
        float cnt = (float)(end - beg);
        float x = dot / fmaxf(cnt, 1.0f) + bl[0];
        out[b] = 1.0f / (1.0f + expf(-x));
    }
}

extern "C" void kernel_launch(void* const* d_in, const int* in_sizes, int n_in,
                              void* d_out, int out_size, void* d_ws, size_t ws_size,
                              hipStream_t stream) {
    const float* x     = (const float*)d_in[0];
    const int*   ei    = (const int*)d_in[1];      // harness converts int64 -> int32
    const int*   batch = (const int*)d_in[2];      // harness converts int64 -> int32
    const float* W1    = (const float*)d_in[3];
    const float* b1    = (const float*)d_in[4];
    const float* W2    = (const float*)d_in[5];
    const float* b2    = (const float*)d_in[6];
    const float* Wl    = (const float*)d_in[7];
    const float* bl    = (const float*)d_in[8];
    float* out = (float*)d_out;

    int N = in_sizes[2];
    int E = in_sizes[1] / 2;
    int F = in_sizes[0] / N;       // 136
    int G = out_size;              // 256 graphs

    int NB = (N + BSZ - 1) >> BSH;   // coarse buckets (<=256 for N<=131072)
    int NC = (E + CH - 1) / CH;      // edge chunks

    char* ws = (char*)d_ws;
    size_t off = 0;
    auto alloc = [&](size_t bytes) -> void* {
        void* p = ws + off;
        off += (bytes + 255) & ~(size_t)255;
        return p;
    };
    float* dinv      = (float*)alloc((size_t)N * 4);
    int*   rowptr    = (int*)alloc((size_t)(N + 1) * 4);
    int*   colidx    = (int*)alloc((size_t)E * 4);
    float* hs        = (float*)alloc((size_t)N * HS * 4);
    float* buf       = (float*)alloc((size_t)N * HS * 4);
    int*   gptr      = (int*)alloc((size_t)(G + 1) * 4);
    int*   blockHist = (int*)alloc((size_t)NB * NC * 4);
    int*   scanned   = (int*)alloc((size_t)NB * NC * 4);
    int*   ebuf      = (int*)hs;     // alias: dead before gemm1 writes hs

    // CSR build (by dst), no global atomics
    histA_kernel<<<NC, 256, 0, stream>>>(ei, E, NB, NC, blockHist);
    scanB_kernel<<<1, 1024, 0, stream>>>(blockHist, NB * NC, scanned, rowptr, N, E);
    scatterB_kernel<<<NC, 256, 0, stream>>>(ei, E, NB, NC, scanned, ebuf);
    buildC_kernel<<<NB, 256, 0, stream>>>(ebuf, scanned, NB, NC, N, E, rowptr, dinv, colidx);
    gbounds_kernel<<<2, 256, 0, stream>>>(batch, N, G, gptr);

    int aggBlocks = ((N * 16) + 255) / 256;

    // layer 1
    gemm_kernel<<<(N + 255) / 256, 256, 0, stream>>>(x, F / 4, F / 4, W1, F, HH, dinv, hs, N);
    agg_kernel<<<aggBlocks, 256, 0, stream>>>(hs, rowptr, colidx, dinv, b1, buf, N);

    // layer 2
    gemm_kernel<<<(N + 255) / 256, 256, 0, stream>>>(buf, HS / 4, 13, W2, HH, HH, dinv, hs, N);
    agg_kernel<<<aggBlocks, 256, 0, stream>>>(hs, rowptr, colidx, dinv, b2, buf, N);

    // pooling + fused head
    pool_head_kernel<<<G, 256, 0, stream>>>(buf, gptr, Wl, bl, out, G);
}

// Round 5
// 460.986 us; speedup vs baseline: 2.5244x; 1.0949x over previous
//
#include <hip/hip_runtime.h>
#include <math.h>

#define HH 50     // hidden features
#define HS 64     // padded row stride (elements); bf16 rows = 128B
#define BSH 9     // bucket shift: 512 nodes per bucket
#define BSZ 512
#define CH 16384  // edges per chunk in bucketed CSR build

__device__ __forceinline__ unsigned int f2bf_pair(float f0, float f1) {
    unsigned int u0 = __float_as_uint(f0);
    unsigned int u1 = __float_as_uint(f1);
    u0 = (u0 + 0x7FFFu + ((u0 >> 16) & 1u)) >> 16;   // RNE
    u1 = (u1 + 0x7FFFu + ((u1 >> 16) & 1u)) >> 16;
    return u0 | (u1 << 16);
}
__device__ __forceinline__ float bf_lo(unsigned int p) { return __uint_as_float(p << 16); }
__device__ __forceinline__ float bf_hi(unsigned int p) { return __uint_as_float(p & 0xFFFF0000u); }

// ---------------- bucketed CSR build (no global atomics) ----------------
__global__ void histA_kernel(const int* __restrict__ ei, int E, int NB, int NC,
                             int* __restrict__ blockHist) {
    __shared__ int hist[256];
    int c = blockIdx.x;
    int tid = threadIdx.x;
    hist[tid] = 0;
    __syncthreads();
    int beg = c * CH, end = min(E, beg + CH);
    for (int i = beg + tid; i < end; i += 256) {
        int d = ei[(size_t)E + i];
        atomicAdd(&hist[d >> BSH], 1);
    }
    __syncthreads();
    if (tid < NB) blockHist[tid * NC + c] = hist[tid];   // bucket-major
}

__global__ void scanB_kernel(const int* __restrict__ blockHist, int M,
                             int* __restrict__ scanned, int* __restrict__ rowptr,
                             int N, int E) {
    __shared__ int part[1024];
    int t = threadIdx.x;
    int chunk = (M + 1023) >> 10;
    int beg = t * chunk; if (beg > M) beg = M;
    int end = beg + chunk; if (end > M) end = M;
    int s = 0;
    for (int i = beg; i < end; i++) s += blockHist[i];
    part[t] = s;
    __syncthreads();
    for (int off = 1; off < 1024; off <<= 1) {
        int v = (t >= off) ? part[t - off] : 0;
        __syncthreads();
        part[t] += v;
        __syncthreads();
    }
    int run = (t == 0) ? 0 : part[t - 1];
    for (int i = beg; i < end; i++) { scanned[i] = run; run += blockHist[i]; }
    if (t == 0) rowptr[N] = E;
}

__global__ void scatterB_kernel(const int* __restrict__ ei, int E, int NB, int NC,
                                const int* __restrict__ scanned, int* __restrict__ ebuf) {
    __shared__ int offs[256];
    int c = blockIdx.x;
    int tid = threadIdx.x;
    if (tid < NB) offs[tid] = scanned[tid * NC + c];
    __syncthreads();
    int beg = c * CH, end = min(E, beg + CH);
    for (int i = beg + tid; i < end; i += 256) {
        int s = ei[i];
        int d = ei[(size_t)E + i];
        int b = d >> BSH;
        int pos = atomicAdd(&offs[b], 1);
        ebuf[pos] = ((d & (BSZ - 1)) << 17) | s;
    }
}

__global__ void buildC_kernel(const int* __restrict__ ebuf, const int* __restrict__ scanned,
                              int NB, int NC, int N, int E,
                              int* __restrict__ rowptr, float* __restrict__ dinv,
                              int* __restrict__ colidx) {
    __shared__ int cnt[BSZ], loc[BSZ], woff[BSZ], part[256];
    int b = blockIdx.x;
    int tid = threadIdx.x;
    int ebeg = scanned[b * NC];
    int eend = (b == NB - 1) ? E : scanned[(b + 1) * NC];
    cnt[tid] = 0; cnt[tid + 256] = 0;
    __syncthreads();
    for (int i = ebeg + tid; i < eend; i += 256) {
        int dl = ebuf[i] >> 17;
        atomicAdd(&cnt[dl], 1);
    }
    __syncthreads();
    int a0 = cnt[2 * tid], a1 = cnt[2 * tid + 1];
    part[tid] = a0 + a1;
    __syncthreads();
    for (int off = 1; off < 256; off <<= 1) {
        int v = (tid >= off) ? part[tid - off] : 0;
        __syncthreads();
        part[tid] += v;
        __syncthreads();
    }
    int base = (tid == 0) ? 0 : part[tid - 1];
    loc[2 * tid] = base;
    loc[2 * tid + 1] = base + a0;
    woff[2 * tid] = base;
    woff[2 * tid + 1] = base + a0;
    __syncthreads();
    for (int dl = tid; dl < BSZ; dl += 256) {
        int node = (b << BSH) + dl;
        if (node < N) {
            rowptr[node] = ebeg + loc[dl];
            dinv[node] = 1.0f / sqrtf((float)(cnt[dl] + 1));   // +1 self loop
        }
    }
    __syncthreads();
    for (int i = ebeg + tid; i < eend; i += 256) {
        int p = ebuf[i];
        int dl = p >> 17;
        int s = p & 0x1FFFF;
        int pos = atomicAdd(&woff[dl], 1);
        colidx[ebeg + pos] = s;
    }
}

// ---------------- graph boundaries (batch is sorted) ----------------
__global__ void gbounds_kernel(const int* __restrict__ batch, int N, int G,
                               int* __restrict__ gptr) {
    int b = blockIdx.x * blockDim.x + threadIdx.x;
    if (b > G) return;
    int lo = 0, hi = N;
    while (lo < hi) {
        int mid = (lo + hi) >> 1;
        if (batch[mid] < b) lo = mid + 1; else hi = mid;
    }
    gptr[b] = lo;
}

// ---------------- GEMM (fp32 input) -> bf16 output rows ----------------
__global__ void gemm_f32_kernel(const float* __restrict__ in, int in_f4_stride, int k4,
                                const float* __restrict__ W, int K, int H,
                                const float* __restrict__ dinv,
                                unsigned int* __restrict__ out, int N) {
    __shared__ float4 Wl[136 * 13];
    int KP = k4 * 4;
    for (int idx = threadIdx.x; idx < KP * 52; idx += blockDim.x) {
        int r = idx / 52, c = idx % 52;
        ((float*)Wl)[idx] = (r < K && c < H) ? W[r * H + c] : 0.0f;
    }
    __syncthreads();
    int row = blockIdx.x * blockDim.x + threadIdx.x;
    if (row >= N) return;
    float4 acc[13];
#pragma unroll
    for (int i = 0; i < 13; i++) acc[i] = make_float4(0.f, 0.f, 0.f, 0.f);
    const float4* inr = (const float4*)in + (size_t)row * in_f4_stride;
    for (int kk = 0; kk < k4; kk++) {
        float4 xv = inr[kk];
        float xs0 = xv.x, xs1 = xv.y, xs2 = xv.z, xs3 = xv.w;
        const float4* w0 = &Wl[(kk * 4 + 0) * 13];
        const float4* w1 = &Wl[(kk * 4 + 1) * 13];
        const float4* w2 = &Wl[(kk * 4 + 2) * 13];
        const float4* w3 = &Wl[(kk * 4 + 3) * 13];
#pragma unroll
        for (int c = 0; c < 13; c++) {
            float4 a = acc[c];
            float4 wa = w0[c];
            a.x += xs0 * wa.x; a.y += xs0 * wa.y; a.z += xs0 * wa.z; a.w += xs0 * wa.w;
            float4 wb = w1[c];
            a.x += xs1 * wb.x; a.y += xs1 * wb.y; a.z += xs1 * wb.z; a.w += xs1 * wb.w;
            float4 wc = w2[c];
            a.x += xs2 * wc.x; a.y += xs2 * wc.y; a.z += xs2 * wc.z; a.w += xs2 * wc.w;
            float4 wd = w3[c];
            a.x += xs3 * wd.x; a.y += xs3 * wd.y; a.z += xs3 * wd.z; a.w += xs3 * wd.w;
            acc[c] = a;
        }
    }
    float dv = dinv[row];
    unsigned int arr[32];
#pragma unroll
    for (int c = 0; c < 13; c++) {
        arr[2 * c]     = f2bf_pair(acc[c].x * dv, acc[c].y * dv);
        arr[2 * c + 1] = f2bf_pair(acc[c].z * dv, acc[c].w * dv);
    }
#pragma unroll
    for (int i = 26; i < 32; i++) arr[i] = 0;
    uint4* outr = (uint4*)(out + (size_t)row * 32);
#pragma unroll
    for (int i = 0; i < 8; i++)
        outr[i] = make_uint4(arr[4 * i], arr[4 * i + 1], arr[4 * i + 2], arr[4 * i + 3]);
}

// ---------------- GEMM (bf16 input rows) -> bf16 output rows ----------------
__global__ void gemm_bf16_kernel(const unsigned int* __restrict__ in, int k4,
                                 const float* __restrict__ W, int K, int H,
                                 const float* __restrict__ dinv,
                                 unsigned int* __restrict__ out, int N) {
    __shared__ float4 Wl[136 * 13];
    int KP = k4 * 4;
    for (int idx = threadIdx.x; idx < KP * 52; idx += blockDim.x) {
        int r = idx / 52, c = idx % 52;
        ((float*)Wl)[idx] = (r < K && c < H) ? W[r * H + c] : 0.0f;
    }
    __syncthreads();
    int row = blockIdx.x * blockDim.x + threadIdx.x;
    if (row >= N) return;
    float4 acc[13];
#pragma unroll
    for (int i = 0; i < 13; i++) acc[i] = make_float4(0.f, 0.f, 0.f, 0.f);
    const uint2* inr = (const uint2*)(in + (size_t)row * 32);
    for (int kk = 0; kk < k4; kk++) {
        uint2 xv = inr[kk];
        float xs0 = bf_lo(xv.x), xs1 = bf_hi(xv.x), xs2 = bf_lo(xv.y), xs3 = bf_hi(xv.y);
        const float4* w0 = &Wl[(kk * 4 + 0) * 13];
        const float4* w1 = &Wl[(kk * 4 + 1) * 13];
        const float4* w2 = &Wl[(kk * 4 + 2) * 13];
        const float4* w3 = &Wl[(kk * 4 + 3) * 13];
#pragma unroll
        for (int c = 0; c < 13; c++) {
            float4 a = acc[c];
            float4 wa = w0[c];
            a.x += xs0 * wa.x; a.y += xs0 * wa.y; a.z += xs0 * wa.z; a.w += xs0 * wa.w;
            float4 wb = w1[c];
            a.x += xs1 * wb.x; a.y += xs1 * wb.y; a.z += xs1 * wb.z; a.w += xs1 * wb.w;
            float4 wc = w2[c];
            a.x += xs2 * wc.x; a.y += xs2 * wc.y; a.z += xs2 * wc.z; a.w += xs2 * wc.w;
            float4 wd = w3[c];
            a.x += xs3 * wd.x; a.y += xs3 * wd.y; a.z += xs3 * wd.z; a.w += xs3 * wd.w;
            acc[c] = a;
        }
    }
    float dv = dinv[row];
    unsigned int arr[32];
#pragma unroll
    for (int c = 0; c < 13; c++) {
        arr[2 * c]     = f2bf_pair(acc[c].x * dv, acc[c].y * dv);
        arr[2 * c + 1] = f2bf_pair(acc[c].z * dv, acc[c].w * dv);
    }
#pragma unroll
    for (int i = 26; i < 32; i++) arr[i] = 0;
    uint4* outr = (uint4*)(out + (size_t)row * 32);
#pragma unroll
    for (int i = 0; i < 8; i++)
        outr[i] = make_uint4(arr[4 * i], arr[4 * i + 1], arr[4 * i + 2], arr[4 * i + 3]);
}

// ---------------- aggregation over bf16 rows ----------------
// thread t -> node t>>4, chunk q=t&15 covers features [4q,4q+4); row = 16 uint2 = 128B
__global__ void agg_kernel(const unsigned int* __restrict__ hs, const int* __restrict__ rowptr,
                           const int* __restrict__ colidx, const float* __restrict__ dinv,
                           const float* __restrict__ bias, unsigned int* __restrict__ out, int N) {
    int t = blockIdx.x * blockDim.x + threadIdx.x;
    int node = t >> 4;
    int q = t & 15;
    if (node >= N) return;
    const uint2* base = (const uint2*)hs;
    uint2 sv = base[(size_t)node * 16 + q];   // self loop term
    float a0 = bf_lo(sv.x), a1 = bf_hi(sv.x), a2 = bf_lo(sv.y), a3 = bf_hi(sv.y);
    int beg = rowptr[node], end = rowptr[node + 1];
    for (int e = beg; e < end; e++) {
        int s = colidx[e];
        uint2 v = base[(size_t)s * 16 + q];
        a0 += bf_lo(v.x); a1 += bf_hi(v.x); a2 += bf_lo(v.y); a3 += bf_hi(v.y);
    }
    float dv = dinv[node];
    int c0 = q * 4;
    float b0 = (c0 + 0 < HH) ? bias[c0 + 0] : 0.0f;
    float b1 = (c0 + 1 < HH) ? bias[c0 + 1] : 0.0f;
    float b2 = (c0 + 2 < HH) ? bias[c0 + 2] : 0.0f;
    float b3 = (c0 + 3 < HH) ? bias[c0 + 3] : 0.0f;
    float r0 = fmaxf(a0 * dv + b0, 0.0f);
    float r1 = fmaxf(a1 * dv + b1, 0.0f);
    float r2 = fmaxf(a2 * dv + b2, 0.0f);
    float r3 = fmaxf(a3 * dv + b3, 0.0f);
    uint2 w;
    if (c0 >= HH) { w.x = 0u; w.y = 0u; }
    else { w.x = f2bf_pair(r0, r1); w.y = f2bf_pair(r2, r3); }
    ((uint2*)out)[(size_t)node * 16 + q] = w;
}

// ---------------- pooling + head over bf16 rows ----------------
__global__ void pool_head_kernel(const unsigned int* __restrict__ h, const int* __restrict__ gptr,
                                 const float* __restrict__ Wl, const float* __restrict__ bl,
                                 float* __restrict__ out, int G) {
    __shared__ float4 red[16][16];    // [sub][q]
    int b = blockIdx.x;
    int t = threadIdx.x;
    int sub = t >> 4, q = t & 15;
    int beg = gptr[b], end = gptr[b + 1];
    const uint2* base = (const uint2*)h;
    float4 acc = make_float4(0.f, 0.f, 0.f, 0.f);
    for (int node = beg + sub; node < end; node += 16) {
        uint2 v = base[(size_t)node * 16 + q];
        acc.x += bf_lo(v.x); acc.y += bf_hi(v.x); acc.z += bf_lo(v.y); acc.w += bf_hi(v.y);
    }
    red[sub][q] = acc;
    __syncthreads();
#pragma unroll
    for (int off = 8; off >= 1; off >>= 1) {
        if (sub < off) {
            float4 a = red[sub][q], c = red[sub + off][q];
            a.x += c.x; a.y += c.y; a.z += c.z; a.w += c.w;
            red[sub][q] = a;
        }
        __syncthreads();
    }
    if (t == 0) {
        const float* g = (const float*)&red[0][0];
        float dot = 0.0f;
        for (int c = 0; c < HH; c++) dot += g[c] * Wl[c];
        float cnt = (float)(end - beg);
        float x = dot / fmaxf(cnt, 1.0f) + bl[0];
        out[b] = 1.0f / (1.0f + expf(-x));
    }
}

extern "C" void kernel_launch(void* const* d_in, const int* in_sizes, int n_in,
                              void* d_out, int out_size, void* d_ws, size_t ws_size,
                              hipStream_t stream) {
    const float* x     = (const float*)d_in[0];
    const int*   ei    = (const int*)d_in[1];
    const int*   batch = (const int*)d_in[2];
    const float* W1    = (const float*)d_in[3];
    const float* b1    = (const float*)d_in[4];
    const float* W2    = (const float*)d_in[5];
    const float* b2    = (const float*)d_in[6];
    const float* Wl    = (const float*)d_in[7];
    const float* bl    = (const float*)d_in[8];
    float* out = (float*)d_out;

    int N = in_sizes[2];
    int E = in_sizes[1] / 2;
    int F = in_sizes[0] / N;       // 136
    int G = out_size;              // 256 graphs

    int NB = (N + BSZ - 1) >> BSH;
    int NC = (E + CH - 1) / CH;

    char* ws = (char*)d_ws;
    size_t off = 0;
    auto alloc = [&](size_t bytes) -> void* {
        void* p = ws + off;
        off += (bytes + 255) & ~(size_t)255;
        return p;
    };
    size_t hsBytes = (size_t)N * HS * 2;                       // bf16 rows
    size_t ebufBytes = (size_t)E * 4;
    float*        dinv      = (float*)alloc((size_t)N * 4);
    int*          rowptr    = (int*)alloc((size_t)(N + 1) * 4);
    int*          colidx    = (int*)alloc(ebufBytes);
    unsigned int* hs        = (unsigned int*)alloc(hsBytes > ebufBytes ? hsBytes : ebufBytes);
    unsigned int* buf       = (unsigned int*)alloc(hsBytes);
    int*          gptr      = (int*)alloc((size_t)(G + 1) * 4);
    int*          blockHist = (int*)alloc((size_t)NB * NC * 4);
    int*          scanned   = (int*)alloc((size_t)NB * NC * 4);
    int*          ebuf      = (int*)hs;     // alias: dead before gemm1 writes hs

    // CSR build (by dst), no global atomics
    histA_kernel<<<NC, 256, 0, stream>>>(ei, E, NB, NC, blockHist);
    scanB_kernel<<<1, 1024, 0, stream>>>(blockHist, NB * NC, scanned, rowptr, N, E);
    scatterB_kernel<<<NC, 256, 0, stream>>>(ei, E, NB, NC, scanned, ebuf);
    buildC_kernel<<<NB, 256, 0, stream>>>(ebuf, scanned, NB, NC, N, E, rowptr, dinv, colidx);
    gbounds_kernel<<<2, 256, 0, stream>>>(batch, N, G, gptr);

    int aggBlocks = ((N * 16) + 255) / 256;

    // layer 1
    gemm_f32_kernel<<<(N + 255) / 256, 256, 0, stream>>>(x, F / 4, F / 4, W1, F, HH, dinv, hs, N);
    agg_kernel<<<aggBlocks, 256, 0, stream>>>(hs, rowptr, colidx, dinv, b1, buf, N);

    // layer 2
    gemm_bf16_kernel<<<(N + 255) / 256, 256, 0, stream>>>(buf, 13, W2, HH, HH, dinv, hs, N);
    agg_kernel<<<aggBlocks, 256, 0, stream>>>(hs, rowptr, colidx, dinv, b2, buf, N);

    // pooling + fused head
    pool_head_kernel<<<G, 256, 0, stream>>>(buf, gptr, Wl, bl, out, G);
}

// Round 6
// 358.281 us; speedup vs baseline: 3.2480x; 1.2867x over previous
//
#include <hip/hip_runtime.h>
#include <math.h>

#define HH 50     // hidden features
#define HS 64     // padded row stride (elements); fp8 rows = 64B, bf16 rows = 128B
#define BSH 9     // bucket shift: 512 nodes per bucket
#define BSZ 512
#define CH 16384  // edges per chunk in bucketed CSR build

typedef float floatx2 __attribute__((ext_vector_type(2)));

__device__ __forceinline__ unsigned int f2bf_pair(float f0, float f1) {
    unsigned int u0 = __float_as_uint(f0);
    unsigned int u1 = __float_as_uint(f1);
    u0 = (u0 + 0x7FFFu + ((u0 >> 16) & 1u)) >> 16;   // RNE
    u1 = (u1 + 0x7FFFu + ((u1 >> 16) & 1u)) >> 16;
    return u0 | (u1 << 16);
}
__device__ __forceinline__ float bf_lo(unsigned int p) { return __uint_as_float(p << 16); }
__device__ __forceinline__ float bf_hi(unsigned int p) { return __uint_as_float(p & 0xFFFF0000u); }

// pack 4 floats -> 4x fp8 e4m3 (hardware RNE)
__device__ __forceinline__ unsigned int pack4_fp8(float f0, float f1, float f2, float f3) {
    int r = 0;
    r = __builtin_amdgcn_cvt_pk_fp8_f32(f0, f1, r, false);
    r = __builtin_amdgcn_cvt_pk_fp8_f32(f2, f3, r, true);
    return (unsigned int)r;
}

// ---------------- bucketed CSR build (no global atomics) ----------------
__global__ void histA_kernel(const int* __restrict__ ei, int E, int NB, int NC,
                             int* __restrict__ blockHist) {
    __shared__ int hist[256];
    int c = blockIdx.x;
    int tid = threadIdx.x;
    hist[tid] = 0;
    __syncthreads();
    int beg = c * CH, end = min(E, beg + CH);
    for (int i = beg + tid; i < end; i += 256) {
        int d = ei[(size_t)E + i];
        atomicAdd(&hist[d >> BSH], 1);
    }
    __syncthreads();
    if (tid < NB) blockHist[tid * NC + c] = hist[tid];   // bucket-major
}

__global__ void scanB_kernel(const int* __restrict__ blockHist, int M,
                             int* __restrict__ scanned, int* __restrict__ rowptr,
                             int N, int E) {
    __shared__ int part[1024];
    int t = threadIdx.x;
    int chunk = (M + 1023) >> 10;
    int beg = t * chunk; if (beg > M) beg = M;
    int end = beg + chunk; if (end > M) end = M;
    int s = 0;
    for (int i = beg; i < end; i++) s += blockHist[i];
    part[t] = s;
    __syncthreads();
    for (int off = 1; off < 1024; off <<= 1) {
        int v = (t >= off) ? part[t - off] : 0;
        __syncthreads();
        part[t] += v;
        __syncthreads();
    }
    int run = (t == 0) ? 0 : part[t - 1];
    for (int i = beg; i < end; i++) { scanned[i] = run; run += blockHist[i]; }
    if (t == 0) rowptr[N] = E;
}

__global__ void scatterB_kernel(const int* __restrict__ ei, int E, int NB, int NC,
                                const int* __restrict__ scanned, int* __restrict__ ebuf) {
    __shared__ int offs[256];
    int c = blockIdx.x;
    int tid = threadIdx.x;
    if (tid < NB) offs[tid] = scanned[tid * NC + c];
    __syncthreads();
    int beg = c * CH, end = min(E, beg + CH);
    for (int i = beg + tid; i < end; i += 256) {
        int s = ei[i];
        int d = ei[(size_t)E + i];
        int b = d >> BSH;
        int pos = atomicAdd(&offs[b], 1);
        ebuf[pos] = ((d & (BSZ - 1)) << 17) | s;
    }
}

__global__ void buildC_kernel(const int* __restrict__ ebuf, const int* __restrict__ scanned,
                              int NB, int NC, int N, int E,
                              int* __restrict__ rowptr, float* __restrict__ dinv,
                              int* __restrict__ colidx) {
    __shared__ int cnt[BSZ], loc[BSZ], woff[BSZ], part[256];
    int b = blockIdx.x;
    int tid = threadIdx.x;
    int ebeg = scanned[b * NC];
    int eend = (b == NB - 1) ? E : scanned[(b + 1) * NC];
    cnt[tid] = 0; cnt[tid + 256] = 0;
    __syncthreads();
    for (int i = ebeg + tid; i < eend; i += 256) {
        int dl = ebuf[i] >> 17;
        atomicAdd(&cnt[dl], 1);
    }
    __syncthreads();
    int a0 = cnt[2 * tid], a1 = cnt[2 * tid + 1];
    part[tid] = a0 + a1;
    __syncthreads();
    for (int off = 1; off < 256; off <<= 1) {
        int v = (tid >= off) ? part[tid - off] : 0;
        __syncthreads();
        part[tid] += v;
        __syncthreads();
    }
    int base = (tid == 0) ? 0 : part[tid - 1];
    loc[2 * tid] = base;
    loc[2 * tid + 1] = base + a0;
    woff[2 * tid] = base;
    woff[2 * tid + 1] = base + a0;
    __syncthreads();
    for (int dl = tid; dl < BSZ; dl += 256) {
        int node = (b << BSH) + dl;
        if (node < N) {
            rowptr[node] = ebeg + loc[dl];
            dinv[node] = 1.0f / sqrtf((float)(cnt[dl] + 1));   // +1 self loop
        }
    }
    __syncthreads();
    for (int i = ebeg + tid; i < eend; i += 256) {
        int p = ebuf[i];
        int dl = p >> 17;
        int s = p & 0x1FFFF;
        int pos = atomicAdd(&woff[dl], 1);
        colidx[ebeg + pos] = s;
    }
}

// ---------------- graph boundaries (batch is sorted) ----------------
__global__ void gbounds_kernel(const int* __restrict__ batch, int N, int G,
                               int* __restrict__ gptr) {
    int b = blockIdx.x * blockDim.x + threadIdx.x;
    if (b > G) return;
    int lo = 0, hi = N;
    while (lo < hi) {
        int mid = (lo + hi) >> 1;
        if (batch[mid] < b) lo = mid + 1; else hi = mid;
    }
    gptr[b] = lo;
}

// ---------------- GEMM (fp32 input) -> fp8 output rows (16 uints = 64B) ----------------
__global__ void gemm_f32_kernel(const float* __restrict__ in, int in_f4_stride, int k4,
                                const float* __restrict__ W, int K, int H,
                                const float* __restrict__ dinv,
                                unsigned int* __restrict__ out, int N) {
    __shared__ float4 Wl[136 * 13];
    int KP = k4 * 4;
    for (int idx = threadIdx.x; idx < KP * 52; idx += blockDim.x) {
        int r = idx / 52, c = idx % 52;
        ((float*)Wl)[idx] = (r < K && c < H) ? W[r * H + c] : 0.0f;
    }
    __syncthreads();
    int row = blockIdx.x * blockDim.x + threadIdx.x;
    if (row >= N) return;
    float4 acc[13];
#pragma unroll
    for (int i = 0; i < 13; i++) acc[i] = make_float4(0.f, 0.f, 0.f, 0.f);
    const float4* inr = (const float4*)in + (size_t)row * in_f4_stride;
    for (int kk = 0; kk < k4; kk++) {
        float4 xv = inr[kk];
        float xs0 = xv.x, xs1 = xv.y, xs2 = xv.z, xs3 = xv.w;
        const float4* w0 = &Wl[(kk * 4 + 0) * 13];
        const float4* w1 = &Wl[(kk * 4 + 1) * 13];
        const float4* w2 = &Wl[(kk * 4 + 2) * 13];
        const float4* w3 = &Wl[(kk * 4 + 3) * 13];
#pragma unroll
        for (int c = 0; c < 13; c++) {
            float4 a = acc[c];
            float4 wa = w0[c];
            a.x += xs0 * wa.x; a.y += xs0 * wa.y; a.z += xs0 * wa.z; a.w += xs0 * wa.w;
            float4 wb = w1[c];
            a.x += xs1 * wb.x; a.y += xs1 * wb.y; a.z += xs1 * wb.z; a.w += xs1 * wb.w;
            float4 wc = w2[c];
            a.x += xs2 * wc.x; a.y += xs2 * wc.y; a.z += xs2 * wc.z; a.w += xs2 * wc.w;
            float4 wd = w3[c];
            a.x += xs3 * wd.x; a.y += xs3 * wd.y; a.z += xs3 * wd.z; a.w += xs3 * wd.w;
            acc[c] = a;
        }
    }
    float dv = dinv[row];
    unsigned int arr[16];
#pragma unroll
    for (int c = 0; c < 13; c++)
        arr[c] = pack4_fp8(acc[c].x * dv, acc[c].y * dv, acc[c].z * dv, acc[c].w * dv);
    arr[13] = 0; arr[14] = 0; arr[15] = 0;
    uint4* outr = (uint4*)(out + (size_t)row * 16);
#pragma unroll
    for (int i = 0; i < 4; i++)
        outr[i] = make_uint4(arr[4 * i], arr[4 * i + 1], arr[4 * i + 2], arr[4 * i + 3]);
}

// ---------------- GEMM (bf16 input rows) -> fp8 output rows ----------------
__global__ void gemm_bf16_kernel(const unsigned int* __restrict__ in, int k4,
                                 const float* __restrict__ W, int K, int H,
                                 const float* __restrict__ dinv,
                                 unsigned int* __restrict__ out, int N) {
    __shared__ float4 Wl[136 * 13];
    int KP = k4 * 4;
    for (int idx = threadIdx.x; idx < KP * 52; idx += blockDim.x) {
        int r = idx / 52, c = idx % 52;
        ((float*)Wl)[idx] = (r < K && c < H) ? W[r * H + c] : 0.0f;
    }
    __syncthreads();
    int row = blockIdx.x * blockDim.x + threadIdx.x;
    if (row >= N) return;
    float4 acc[13];
#pragma unroll
    for (int i = 0; i < 13; i++) acc[i] = make_float4(0.f, 0.f, 0.f, 0.f);
    const uint2* inr = (const uint2*)(in + (size_t)row * 32);
    for (int kk = 0; kk < k4; kk++) {
        uint2 xv = inr[kk];
        float xs0 = bf_lo(xv.x), xs1 = bf_hi(xv.x), xs2 = bf_lo(xv.y), xs3 = bf_hi(xv.y);
        const float4* w0 = &Wl[(kk * 4 + 0) * 13];
        const float4* w1 = &Wl[(kk * 4 + 1) * 13];
        const float4* w2 = &Wl[(kk * 4 + 2) * 13];
        const float4* w3 = &Wl[(kk * 4 + 3) * 13];
#pragma unroll
        for (int c = 0; c < 13; c++) {
            float4 a = acc[c];
            float4 wa = w0[c];
            a.x += xs0 * wa.x; a.y += xs0 * wa.y; a.z += xs0 * wa.z; a.w += xs0 * wa.w;
            float4 wb = w1[c];
            a.x += xs1 * wb.x; a.y += xs1 * wb.y; a.z += xs1 * wb.z; a.w += xs1 * wb.w;
            float4 wc = w2[c];
            a.x += xs2 * wc.x; a.y += xs2 * wc.y; a.z += xs2 * wc.z; a.w += xs2 * wc.w;
            float4 wd = w3[c];
            a.x += xs3 * wd.x; a.y += xs3 * wd.y; a.z += xs3 * wd.z; a.w += xs3 * wd.w;
            acc[c] = a;
        }
    }
    float dv = dinv[row];
    unsigned int arr[16];
#pragma unroll
    for (int c = 0; c < 13; c++)
        arr[c] = pack4_fp8(acc[c].x * dv, acc[c].y * dv, acc[c].z * dv, acc[c].w * dv);
    arr[13] = 0; arr[14] = 0; arr[15] = 0;
    uint4* outr = (uint4*)(out + (size_t)row * 16);
#pragma unroll
    for (int i = 0; i < 4; i++)
        outr[i] = make_uint4(arr[4 * i], arr[4 * i + 1], arr[4 * i + 2], arr[4 * i + 3]);
}

// ---------------- aggregation over fp8 rows -> bf16 out rows ----------------
// thread t -> node t>>4, lane q=t&15 covers features [4q,4q+4); fp8 row = 16 uints = 64B
__global__ void agg_kernel(const unsigned int* __restrict__ hs, const int* __restrict__ rowptr,
                           const int* __restrict__ colidx, const float* __restrict__ dinv,
                           const float* __restrict__ bias, unsigned int* __restrict__ out, int N) {
    int t = blockIdx.x * blockDim.x + threadIdx.x;
    int node = t >> 4;
    int q = t & 15;
    if (node >= N) return;
    const unsigned int* basq = hs + q;
    unsigned int sv = basq[(size_t)node * 16];   // self loop term
    floatx2 plo = __builtin_amdgcn_cvt_pk_f32_fp8((int)sv, false);
    floatx2 phi = __builtin_amdgcn_cvt_pk_f32_fp8((int)sv, true);
    float a0 = plo[0], a1 = plo[1], a2 = phi[0], a3 = phi[1];
    int beg = rowptr[node], end = rowptr[node + 1];
    int e = beg;
    for (; e + 2 <= end; e += 2) {
        int s0 = colidx[e];
        int s1 = colidx[e + 1];
        unsigned int v0 = basq[(size_t)s0 * 16];
        unsigned int v1 = basq[(size_t)s1 * 16];
        floatx2 l0 = __builtin_amdgcn_cvt_pk_f32_fp8((int)v0, false);
        floatx2 h0 = __builtin_amdgcn_cvt_pk_f32_fp8((int)v0, true);
        floatx2 l1 = __builtin_amdgcn_cvt_pk_f32_fp8((int)v1, false);
        floatx2 h1 = __builtin_amdgcn_cvt_pk_f32_fp8((int)v1, true);
        a0 += l0[0] + l1[0]; a1 += l0[1] + l1[1];
        a2 += h0[0] + h1[0]; a3 += h0[1] + h1[1];
    }
    if (e < end) {
        int s0 = colidx[e];
        unsigned int v0 = basq[(size_t)s0 * 16];
        floatx2 l0 = __builtin_amdgcn_cvt_pk_f32_fp8((int)v0, false);
        floatx2 h0 = __builtin_amdgcn_cvt_pk_f32_fp8((int)v0, true);
        a0 += l0[0]; a1 += l0[1]; a2 += h0[0]; a3 += h0[1];
    }
    float dv = dinv[node];
    int c0 = q * 4;
    float b0 = (c0 + 0 < HH) ? bias[c0 + 0] : 0.0f;
    float b1 = (c0 + 1 < HH) ? bias[c0 + 1] : 0.0f;
    float b2 = (c0 + 2 < HH) ? bias[c0 + 2] : 0.0f;
    float b3 = (c0 + 3 < HH) ? bias[c0 + 3] : 0.0f;
    float r0 = fmaxf(a0 * dv + b0, 0.0f);
    float r1 = fmaxf(a1 * dv + b1, 0.0f);
    float r2 = fmaxf(a2 * dv + b2, 0.0f);
    float r3 = fmaxf(a3 * dv + b3, 0.0f);
    uint2 w;
    if (c0 >= HH) { w.x = 0u; w.y = 0u; }
    else { w.x = f2bf_pair(r0, r1); w.y = f2bf_pair(r2, r3); }
    ((uint2*)out)[(size_t)node * 16 + q] = w;
}

// ---------------- pooling + head over bf16 rows ----------------
__global__ void pool_head_kernel(const unsigned int* __restrict__ h, const int* __restrict__ gptr,
                                 const float* __restrict__ Wl, const float* __restrict__ bl,
                                 float* __restrict__ out, int G) {
    __shared__ float4 red[16][16];    // [sub][q]
    int b = blockIdx.x;
    int t = threadIdx.x;
    int sub = t >> 4, q = t & 15;
    int beg = gptr[b], end = gptr[b + 1];
    const uint2* base = (const uint2*)h;
    float4 acc = make_float4(0.f, 0.f, 0.f, 0.f);
    for (int node = beg + sub; node < end; node += 16) {
        uint2 v = base[(size_t)node * 16 + q];
        acc.x += bf_lo(v.x); acc.y += bf_hi(v.x); acc.z += bf_lo(v.y); acc.w += bf_hi(v.y);
    }
    red[sub][q] = acc;
    __syncthreads();
#pragma unroll
    for (int off = 8; off >= 1; off >>= 1) {
        if (sub < off) {
            float4 a = red[sub][q], c = red[sub + off][q];
            a.x += c.x; a.y += c.y; a.z += c.z; a.w += c.w;
            red[sub][q] = a;
        }
        __syncthreads();
    }
    if (t == 0) {
        const float* g = (const float*)&red[0][0];
        float dot = 0.0f;
        for (int c = 0; c < HH; c++) dot += g[c] * Wl[c];
        float cnt = (float)(end - beg);
        float x = dot / fmaxf(cnt, 1.0f) + bl[0];
        out[b] = 1.0f / (1.0f + expf(-x));
    }
}

extern "C" void kernel_launch(void* const* d_in, const int* in_sizes, int n_in,
                              void* d_out, int out_size, void* d_ws, size_t ws_size,
                              hipStream_t stream) {
    const float* x     = (const float*)d_in[0];
    const int*   ei    = (const int*)d_in[1];
    const int*   batch = (const int*)d_in[2];
    const float* W1    = (const float*)d_in[3];
    const float* b1    = (const float*)d_in[4];
    const float* W2    = (const float*)d_in[5];
    const float* b2    = (const float*)d_in[6];
    const float* Wl    = (const float*)d_in[7];
    const float* bl    = (const float*)d_in[8];
    float* out = (float*)d_out;

    int N = in_sizes[2];
    int E = in_sizes[1] / 2;
    int F = in_sizes[0] / N;       // 136
    int G = out_size;              // 256 graphs

    int NB = (N + BSZ - 1) >> BSH;
    int NC = (E + CH - 1) / CH;

    char* ws = (char*)d_ws;
    size_t off = 0;
    auto alloc = [&](size_t bytes) -> void* {
        void* p = ws + off;
        off += (bytes + 255) & ~(size_t)255;
        return p;
    };
    size_t hsBytes   = (size_t)N * HS;       // fp8 rows (64B)
    size_t bufBytes  = (size_t)N * HS * 2;   // bf16 rows (128B)
    size_t ebufBytes = (size_t)E * 4;
    float*        dinv      = (float*)alloc((size_t)N * 4);
    int*          rowptr    = (int*)alloc((size_t)(N + 1) * 4);
    int*          colidx    = (int*)alloc(ebufBytes);
    unsigned int* hs        = (unsigned int*)alloc(hsBytes > ebufBytes ? hsBytes : ebufBytes);
    unsigned int* buf       = (unsigned int*)alloc(bufBytes);
    int*          gptr      = (int*)alloc((size_t)(G + 1) * 4);
    int*          blockHist = (int*)alloc((size_t)NB * NC * 4);
    int*          scanned   = (int*)alloc((size_t)NB * NC * 4);
    int*          ebuf      = (int*)hs;     // alias: dead before gemm1 writes hs

    // CSR build (by dst), no global atomics
    histA_kernel<<<NC, 256, 0, stream>>>(ei, E, NB, NC, blockHist);
    scanB_kernel<<<1, 1024, 0, stream>>>(blockHist, NB * NC, scanned, rowptr, N, E);
    scatterB_kernel<<<NC, 256, 0, stream>>>(ei, E, NB, NC, scanned, ebuf);
    buildC_kernel<<<NB, 256, 0, stream>>>(ebuf, scanned, NB, NC, N, E, rowptr, dinv, colidx);
    gbounds_kernel<<<2, 256, 0, stream>>>(batch, N, G, gptr);

    int aggBlocks = ((N * 16) + 255) / 256;

    // layer 1
    gemm_f32_kernel<<<(N + 255) / 256, 256, 0, stream>>>(x, F / 4, F / 4, W1, F, HH, dinv, hs, N);
    agg_kernel<<<aggBlocks, 256, 0, stream>>>(hs, rowptr, colidx, dinv, b1, buf, N);

    // layer 2
    gemm_bf16_kernel<<<(N + 255) / 256, 256, 0, stream>>>(buf, 13, W2, HH, HH, dinv, hs, N);
    agg_kernel<<<aggBlocks, 256, 0, stream>>>(hs, rowptr, colidx, dinv, b2, buf, N);

    // pooling + fused head
    pool_head_kernel<<<G, 256, 0, stream>>>(buf, gptr, Wl, bl, out, G);
}

// Round 7
// 357.398 us; speedup vs baseline: 3.2560x; 1.0025x over previous
//
#include <hip/hip_runtime.h>
#include <math.h>

#define HH 50     // hidden features
#define HS 64     // padded row stride (elements); fp8 rows = 64B, bf16 rows = 128B
#define BSH 9     // bucket shift: 512 nodes per bucket
#define BSZ 512
#define CH 16384  // edges per chunk in bucketed CSR build

typedef float floatx2 __attribute__((ext_vector_type(2)));

__device__ __forceinline__ unsigned int f2bf_pair(float f0, float f1) {
    unsigned int u0 = __float_as_uint(f0);
    unsigned int u1 = __float_as_uint(f1);
    u0 = (u0 + 0x7FFFu + ((u0 >> 16) & 1u)) >> 16;   // RNE
    u1 = (u1 + 0x7FFFu + ((u1 >> 16) & 1u)) >> 16;
    return u0 | (u1 << 16);
}
__device__ __forceinline__ float bf_lo(unsigned int p) { return __uint_as_float(p << 16); }
__device__ __forceinline__ float bf_hi(unsigned int p) { return __uint_as_float(p & 0xFFFF0000u); }

// pack 4 floats -> 4x fp8 e4m3 (hardware RNE)
__device__ __forceinline__ unsigned int pack4_fp8(float f0, float f1, float f2, float f3) {
    int r = 0;
    r = __builtin_amdgcn_cvt_pk_fp8_f32(f0, f1, r, false);
    r = __builtin_amdgcn_cvt_pk_fp8_f32(f2, f3, r, true);
    return (unsigned int)r;
}

// ---------------- bucketed CSR build (no global atomics) ----------------
__global__ void histA_kernel(const int* __restrict__ ei, int E, int NB, int NC,
                             int* __restrict__ blockHist) {
    __shared__ int hist[256];
    int c = blockIdx.x;
    int tid = threadIdx.x;
    hist[tid] = 0;
    __syncthreads();
    int beg = c * CH, end = min(E, beg + CH);
    for (int i = beg + tid; i < end; i += 256) {
        int d = ei[(size_t)E + i];
        atomicAdd(&hist[d >> BSH], 1);
    }
    __syncthreads();
    if (tid < NB) blockHist[tid * NC + c] = hist[tid];   // bucket-major
}

__global__ void scanB_kernel(const int* __restrict__ blockHist, int M,
                             int* __restrict__ scanned, int* __restrict__ rowptr,
                             int N, int E) {
    __shared__ int part[1024];
    int t = threadIdx.x;
    int chunk = (M + 1023) >> 10;
    int beg = t * chunk; if (beg > M) beg = M;
    int end = beg + chunk; if (end > M) end = M;
    int s = 0;
    for (int i = beg; i < end; i++) s += blockHist[i];
    part[t] = s;
    __syncthreads();
    for (int off = 1; off < 1024; off <<= 1) {
        int v = (t >= off) ? part[t - off] : 0;
        __syncthreads();
        part[t] += v;
        __syncthreads();
    }
    int run = (t == 0) ? 0 : part[t - 1];
    for (int i = beg; i < end; i++) { scanned[i] = run; run += blockHist[i]; }
    if (t == 0) rowptr[N] = E;
}

__global__ void scatterB_kernel(const int* __restrict__ ei, int E, int NB, int NC,
                                const int* __restrict__ scanned, int* __restrict__ ebuf) {
    __shared__ int offs[256];
    int c = blockIdx.x;
    int tid = threadIdx.x;
    if (tid < NB) offs[tid] = scanned[tid * NC + c];
    __syncthreads();
    int beg = c * CH, end = min(E, beg + CH);
    for (int i = beg + tid; i < end; i += 256) {
        int s = ei[i];
        int d = ei[(size_t)E + i];
        int b = d >> BSH;
        int pos = atomicAdd(&offs[b], 1);
        ebuf[pos] = ((d & (BSZ - 1)) << 17) | s;
    }
}

__global__ void buildC_kernel(const int* __restrict__ ebuf, const int* __restrict__ scanned,
                              int NB, int NC, int N, int E,
                              int* __restrict__ rowptr, float* __restrict__ dinv,
                              int* __restrict__ colidx) {
    __shared__ int cnt[BSZ], loc[BSZ], woff[BSZ], part[256];
    int b = blockIdx.x;
    int tid = threadIdx.x;
    int ebeg = scanned[b * NC];
    int eend = (b == NB - 1) ? E : scanned[(b + 1) * NC];
    cnt[tid] = 0; cnt[tid + 256] = 0;
    __syncthreads();
    for (int i = ebeg + tid; i < eend; i += 256) {
        int dl = ebuf[i] >> 17;
        atomicAdd(&cnt[dl], 1);
    }
    __syncthreads();
    int a0 = cnt[2 * tid], a1 = cnt[2 * tid + 1];
    part[tid] = a0 + a1;
    __syncthreads();
    for (int off = 1; off < 256; off <<= 1) {
        int v = (tid >= off) ? part[tid - off] : 0;
        __syncthreads();
        part[tid] += v;
        __syncthreads();
    }
    int base = (tid == 0) ? 0 : part[tid - 1];
    loc[2 * tid] = base;
    loc[2 * tid + 1] = base + a0;
    woff[2 * tid] = base;
    woff[2 * tid + 1] = base + a0;
    __syncthreads();
    for (int dl = tid; dl < BSZ; dl += 256) {
        int node = (b << BSH) + dl;
        if (node < N) {
            rowptr[node] = ebeg + loc[dl];
            dinv[node] = 1.0f / sqrtf((float)(cnt[dl] + 1));   // +1 self loop
        }
    }
    __syncthreads();
    for (int i = ebeg + tid; i < eend; i += 256) {
        int p = ebuf[i];
        int dl = p >> 17;
        int s = p & 0x1FFFF;
        int pos = atomicAdd(&woff[dl], 1);
        colidx[ebeg + pos] = s;
    }
}

// ---------------- graph boundaries (batch is sorted) ----------------
__global__ void gbounds_kernel(const int* __restrict__ batch, int N, int G,
                               int* __restrict__ gptr) {
    int b = blockIdx.x * blockDim.x + threadIdx.x;
    if (b > G) return;
    int lo = 0, hi = N;
    while (lo < hi) {
        int mid = (lo + hi) >> 1;
        if (batch[mid] < b) lo = mid + 1; else hi = mid;
    }
    gptr[b] = lo;
}

// ---------------- GEMM (fp32 input) -> fp8 rows; 4 lanes/row x 16 cols ----------------
// block = 256 threads = 64 rows x 4 col-groups. W in LDS padded to [K][64].
__global__ void gemm_f32_kernel(const float* __restrict__ in, int k4,
                                const float* __restrict__ W, int K, int H,
                                const float* __restrict__ dinv,
                                unsigned int* __restrict__ out, int N) {
    __shared__ float Wl[136 * 64];
    int KP = k4 * 4;
    for (int idx = threadIdx.x; idx < KP * 64; idx += 256) {
        int r = idx >> 6, c = idx & 63;
        Wl[idx] = (r < K && c < H) ? W[r * H + c] : 0.0f;
    }
    __syncthreads();
    int row = blockIdx.x * 64 + (threadIdx.x >> 2);
    int g = threadIdx.x & 3;
    if (row >= N) return;
    float4 acc[4];
#pragma unroll
    for (int i = 0; i < 4; i++) acc[i] = make_float4(0.f, 0.f, 0.f, 0.f);
    const float4* inr = (const float4*)in + (size_t)row * k4;
    const float4* Wg = (const float4*)Wl + g * 4;   // float4-index: k*16 + g*4 + c
    for (int kk = 0; kk < k4; kk++) {
        float4 xv = inr[kk];
#pragma unroll
        for (int j = 0; j < 4; j++) {
            float xs = (j == 0) ? xv.x : (j == 1) ? xv.y : (j == 2) ? xv.z : xv.w;
            const float4* wrow = Wg + (size_t)(kk * 4 + j) * 16;
#pragma unroll
            for (int c = 0; c < 4; c++) {
                float4 w = wrow[c];
                acc[c].x += xs * w.x; acc[c].y += xs * w.y;
                acc[c].z += xs * w.z; acc[c].w += xs * w.w;
            }
        }
    }
    float dv = dinv[row];
    uint4 o;
    o.x = pack4_fp8(acc[0].x * dv, acc[0].y * dv, acc[0].z * dv, acc[0].w * dv);
    o.y = pack4_fp8(acc[1].x * dv, acc[1].y * dv, acc[1].z * dv, acc[1].w * dv);
    o.z = pack4_fp8(acc[2].x * dv, acc[2].y * dv, acc[2].z * dv, acc[2].w * dv);
    o.w = pack4_fp8(acc[3].x * dv, acc[3].y * dv, acc[3].z * dv, acc[3].w * dv);
    ((uint4*)(out + (size_t)row * 16))[g] = o;
}

// ---------------- GEMM (bf16 input rows) -> fp8 rows; 4 lanes/row x 16 cols ----------------
__global__ void gemm_bf16_kernel(const unsigned int* __restrict__ in, int k4,
                                 const float* __restrict__ W, int K, int H,
                                 const float* __restrict__ dinv,
                                 unsigned int* __restrict__ out, int N) {
    __shared__ float Wl[52 * 64];
    int KP = k4 * 4;
    for (int idx = threadIdx.x; idx < KP * 64; idx += 256) {
        int r = idx >> 6, c = idx & 63;
        Wl[idx] = (r < K && c < H) ? W[r * H + c] : 0.0f;
    }
    __syncthreads();
    int row = blockIdx.x * 64 + (threadIdx.x >> 2);
    int g = threadIdx.x & 3;
    if (row >= N) return;
    float4 acc[4];
#pragma unroll
    for (int i = 0; i < 4; i++) acc[i] = make_float4(0.f, 0.f, 0.f, 0.f);
    const uint2* inr = (const uint2*)(in + (size_t)row * 32);
    const float4* Wg = (const float4*)Wl + g * 4;
    for (int kk = 0; kk < k4; kk++) {
        uint2 xv = inr[kk];
        float xs0 = bf_lo(xv.x), xs1 = bf_hi(xv.x), xs2 = bf_lo(xv.y), xs3 = bf_hi(xv.y);
#pragma unroll
        for (int j = 0; j < 4; j++) {
            float xs = (j == 0) ? xs0 : (j == 1) ? xs1 : (j == 2) ? xs2 : xs3;
            const float4* wrow = Wg + (size_t)(kk * 4 + j) * 16;
#pragma unroll
            for (int c = 0; c < 4; c++) {
                float4 w = wrow[c];
                acc[c].x += xs * w.x; acc[c].y += xs * w.y;
                acc[c].z += xs * w.z; acc[c].w += xs * w.w;
            }
        }
    }
    float dv = dinv[row];
    uint4 o;
    o.x = pack4_fp8(acc[0].x * dv, acc[0].y * dv, acc[0].z * dv, acc[0].w * dv);
    o.y = pack4_fp8(acc[1].x * dv, acc[1].y * dv, acc[1].z * dv, acc[1].w * dv);
    o.z = pack4_fp8(acc[2].x * dv, acc[2].y * dv, acc[2].z * dv, acc[2].w * dv);
    o.w = pack4_fp8(acc[3].x * dv, acc[3].y * dv, acc[3].z * dv, acc[3].w * dv);
    ((uint4*)(out + (size_t)row * 16))[g] = o;
}

// ---------------- aggregation over fp8 rows -> bf16 out rows ----------------
// thread t -> node t>>4, lane q=t&15 covers features [4q,4q+4); fp8 row = 16 uints = 64B
__global__ void agg_kernel(const unsigned int* __restrict__ hs, const int* __restrict__ rowptr,
                           const int* __restrict__ colidx, const float* __restrict__ dinv,
                           const float* __restrict__ bias, unsigned int* __restrict__ out, int N) {
    int t = blockIdx.x * blockDim.x + threadIdx.x;
    int node = t >> 4;
    int q = t & 15;
    if (node >= N) return;
    const unsigned int* basq = hs + q;
    unsigned int sv = basq[(size_t)node * 16];   // self loop term
    floatx2 plo = __builtin_amdgcn_cvt_pk_f32_fp8((int)sv, false);
    floatx2 phi = __builtin_amdgcn_cvt_pk_f32_fp8((int)sv, true);
    float a0 = plo[0], a1 = plo[1], a2 = phi[0], a3 = phi[1];
    int beg = rowptr[node], end = rowptr[node + 1];
    int e = beg;
    for (; e + 2 <= end; e += 2) {
        int s0 = colidx[e];
        int s1 = colidx[e + 1];
        unsigned int v0 = basq[(size_t)s0 * 16];
        unsigned int v1 = basq[(size_t)s1 * 16];
        floatx2 l0 = __builtin_amdgcn_cvt_pk_f32_fp8((int)v0, false);
        floatx2 h0 = __builtin_amdgcn_cvt_pk_f32_fp8((int)v0, true);
        floatx2 l1 = __builtin_amdgcn_cvt_pk_f32_fp8((int)v1, false);
        floatx2 h1 = __builtin_amdgcn_cvt_pk_f32_fp8((int)v1, true);
        a0 += l0[0] + l1[0]; a1 += l0[1] + l1[1];
        a2 += h0[0] + h1[0]; a3 += h0[1] + h1[1];
    }
    if (e < end) {
        int s0 = colidx[e];
        unsigned int v0 = basq[(size_t)s0 * 16];
        floatx2 l0 = __builtin_amdgcn_cvt_pk_f32_fp8((int)v0, false);
        floatx2 h0 = __builtin_amdgcn_cvt_pk_f32_fp8((int)v0, true);
        a0 += l0[0]; a1 += l0[1]; a2 += h0[0]; a3 += h0[1];
    }
    float dv = dinv[node];
    int c0 = q * 4;
    float b0 = (c0 + 0 < HH) ? bias[c0 + 0] : 0.0f;
    float b1 = (c0 + 1 < HH) ? bias[c0 + 1] : 0.0f;
    float b2 = (c0 + 2 < HH) ? bias[c0 + 2] : 0.0f;
    float b3 = (c0 + 3 < HH) ? bias[c0 + 3] : 0.0f;
    float r0 = fmaxf(a0 * dv + b0, 0.0f);
    float r1 = fmaxf(a1 * dv + b1, 0.0f);
    float r2 = fmaxf(a2 * dv + b2, 0.0f);
    float r3 = fmaxf(a3 * dv + b3, 0.0f);
    uint2 w;
    if (c0 >= HH) { w.x = 0u; w.y = 0u; }
    else { w.x = f2bf_pair(r0, r1); w.y = f2bf_pair(r2, r3); }
    ((uint2*)out)[(size_t)node * 16 + q] = w;
}

// ---------------- pooling + head over bf16 rows ----------------
__global__ void pool_head_kernel(const unsigned int* __restrict__ h, const int* __restrict__ gptr,
                                 const float* __restrict__ Wl, const float* __restrict__ bl,
                                 float* __restrict__ out, int G) {
    __shared__ float4 red[16][16];    // [sub][q]
    int b = blockIdx.x;
    int t = threadIdx.x;
    int sub = t >> 4, q = t & 15;
    int beg = gptr[b], end = gptr[b + 1];
    const uint2* base = (const uint2*)h;
    float4 acc = make_float4(0.f, 0.f, 0.f, 0.f);
    for (int node = beg + sub; node < end; node += 16) {
        uint2 v = base[(size_t)node * 16 + q];
        acc.x += bf_lo(v.x); acc.y += bf_hi(v.x); acc.z += bf_lo(v.y); acc.w += bf_hi(v.y);
    }
    red[sub][q] = acc;
    __syncthreads();
#pragma unroll
    for (int off = 8; off >= 1; off >>= 1) {
        if (sub < off) {
            float4 a = red[sub][q], c = red[sub + off][q];
            a.x += c.x; a.y += c.y; a.z += c.z; a.w += c.w;
            red[sub][q] = a;
        }
        __syncthreads();
    }
    if (t == 0) {
        const float* g = (const float*)&red[0][0];
        float dot = 0.0f;
        for (int c = 0; c < HH; c++) dot += g[c] * Wl[c];
        float cnt = (float)(end - beg);
        float x = dot / fmaxf(cnt, 1.0f) + bl[0];
        out[b] = 1.0f / (1.0f + expf(-x));
    }
}

extern "C" void kernel_launch(void* const* d_in, const int* in_sizes, int n_in,
                              void* d_out, int out_size, void* d_ws, size_t ws_size,
                              hipStream_t stream) {
    const float* x     = (const float*)d_in[0];
    const int*   ei    = (const int*)d_in[1];
    const int*   batch = (const int*)d_in[2];
    const float* W1    = (const float*)d_in[3];
    const float* b1    = (const float*)d_in[4];
    const float* W2    = (const float*)d_in[5];
    const float* b2    = (const float*)d_in[6];
    const float* Wl    = (const float*)d_in[7];
    const float* bl    = (const float*)d_in[8];
    float* out = (float*)d_out;

    int N = in_sizes[2];
    int E = in_sizes[1] / 2;
    int F = in_sizes[0] / N;       // 136
    int G = out_size;              // 256 graphs

    int NB = (N + BSZ - 1) >> BSH;
    int NC = (E + CH - 1) / CH;

    char* ws = (char*)d_ws;
    size_t off = 0;
    auto alloc = [&](size_t bytes) -> void* {
        void* p = ws + off;
        off += (bytes + 255) & ~(size_t)255;
        return p;
    };
    size_t hsBytes   = (size_t)N * HS;       // fp8 rows (64B)
    size_t bufBytes  = (size_t)N * HS * 2;   // bf16 rows (128B)
    size_t ebufBytes = (size_t)E * 4;
    float*        dinv      = (float*)alloc((size_t)N * 4);
    int*          rowptr    = (int*)alloc((size_t)(N + 1) * 4);
    int*          colidx    = (int*)alloc(ebufBytes);
    unsigned int* hs        = (unsigned int*)alloc(hsBytes > ebufBytes ? hsBytes : ebufBytes);
    unsigned int* buf       = (unsigned int*)alloc(bufBytes);
    int*          gptr      = (int*)alloc((size_t)(G + 1) * 4);
    int*          blockHist = (int*)alloc((size_t)NB * NC * 4);
    int*          scanned   = (int*)alloc((size_t)NB * NC * 4);
    int*          ebuf      = (int*)hs;     // alias: dead before gemm1 writes hs

    // CSR build (by dst), no global atomics
    histA_kernel<<<NC, 256, 0, stream>>>(ei, E, NB, NC, blockHist);
    scanB_kernel<<<1, 1024, 0, stream>>>(blockHist, NB * NC, scanned, rowptr, N, E);
    scatterB_kernel<<<NC, 256, 0, stream>>>(ei, E, NB, NC, scanned, ebuf);
    buildC_kernel<<<NB, 256, 0, stream>>>(ebuf, scanned, NB, NC, N, E, rowptr, dinv, colidx);
    gbounds_kernel<<<2, 256, 0, stream>>>(batch, N, G, gptr);

    int aggBlocks = ((N * 16) + 255) / 256;
    int gemmBlocks = (N + 63) / 64;

    // layer 1
    gemm_f32_kernel<<<gemmBlocks, 256, 0, stream>>>(x, F / 4, W1, F, HH, dinv, hs, N);
    agg_kernel<<<aggBlocks, 256, 0, stream>>>(hs, rowptr, colidx, dinv, b1, buf, N);

    // layer 2
    gemm_bf16_kernel<<<gemmBlocks, 256, 0, stream>>>(buf, 13, W2, HH, HH, dinv, hs, N);
    agg_kernel<<<aggBlocks, 256, 0, stream>>>(hs, rowptr, colidx, dinv, b2, buf, N);

    // pooling + fused head
    pool_head_kernel<<<G, 256, 0, stream>>>(buf, gptr, Wl, bl, out, G);
}

// Round 8
// 350.312 us; speedup vs baseline: 3.3219x; 1.0202x over previous
//
#include <hip/hip_runtime.h>
#include <math.h>

#define HH 50     // hidden features
#define HS 64     // padded row stride (elements); fp8 rows = 64B, bf16 rows = 128B
#define BSH 9     // bucket shift: 512 nodes per bucket
#define BSZ 512
#define CH 16384  // edges per chunk in bucketed CSR build

typedef float floatx2 __attribute__((ext_vector_type(2)));

__device__ __forceinline__ unsigned int f2bf_pair(float f0, float f1) {
    unsigned int u0 = __float_as_uint(f0);
    unsigned int u1 = __float_as_uint(f1);
    u0 = (u0 + 0x7FFFu + ((u0 >> 16) & 1u)) >> 16;   // RNE
    u1 = (u1 + 0x7FFFu + ((u1 >> 16) & 1u)) >> 16;
    return u0 | (u1 << 16);
}
__device__ __forceinline__ float bf_lo(unsigned int p) { return __uint_as_float(p << 16); }
__device__ __forceinline__ float bf_hi(unsigned int p) { return __uint_as_float(p & 0xFFFF0000u); }

// pack 4 floats -> 4x fp8 e4m3 (hardware RNE)
__device__ __forceinline__ unsigned int pack4_fp8(float f0, float f1, float f2, float f3) {
    int r = 0;
    r = __builtin_amdgcn_cvt_pk_fp8_f32(f0, f1, r, false);
    r = __builtin_amdgcn_cvt_pk_fp8_f32(f2, f3, r, true);
    return (unsigned int)r;
}

// ---------------- bucketed CSR build (no global atomics) ----------------
__global__ void histA_kernel(const int* __restrict__ ei, int E, int NB, int NC,
                             int* __restrict__ blockHist) {
    __shared__ int hist[256];
    int c = blockIdx.x;
    int tid = threadIdx.x;
    hist[tid] = 0;
    __syncthreads();
    int beg = c * CH, end = min(E, beg + CH);
    for (int i = beg + tid; i < end; i += 256) {
        int d = ei[(size_t)E + i];
        atomicAdd(&hist[d >> BSH], 1);
    }
    __syncthreads();
    if (tid < NB) blockHist[tid * NC + c] = hist[tid];   // bucket-major
}

__global__ void scanB_kernel(const int* __restrict__ blockHist, int M,
                             int* __restrict__ scanned, int* __restrict__ rowptr,
                             int N, int E) {
    __shared__ int part[1024];
    int t = threadIdx.x;
    int chunk = (M + 1023) >> 10;
    int beg = t * chunk; if (beg > M) beg = M;
    int end = beg + chunk; if (end > M) end = M;
    int s = 0;
    for (int i = beg; i < end; i++) s += blockHist[i];
    part[t] = s;
    __syncthreads();
    for (int off = 1; off < 1024; off <<= 1) {
        int v = (t >= off) ? part[t - off] : 0;
        __syncthreads();
        part[t] += v;
        __syncthreads();
    }
    int run = (t == 0) ? 0 : part[t - 1];
    for (int i = beg; i < end; i++) { scanned[i] = run; run += blockHist[i]; }
    if (t == 0) rowptr[N] = E;
}

__global__ void scatterB_kernel(const int* __restrict__ ei, int E, int NB, int NC,
                                const int* __restrict__ scanned, int* __restrict__ ebuf) {
    __shared__ int offs[256];
    int c = blockIdx.x;
    int tid = threadIdx.x;
    if (tid < NB) offs[tid] = scanned[tid * NC + c];
    __syncthreads();
    int beg = c * CH, end = min(E, beg + CH);
    for (int i = beg + tid; i < end; i += 256) {
        int s = ei[i];
        int d = ei[(size_t)E + i];
        int b = d >> BSH;
        int pos = atomicAdd(&offs[b], 1);
        ebuf[pos] = ((d & (BSZ - 1)) << 17) | s;
    }
}

__global__ void buildC_kernel(const int* __restrict__ ebuf, const int* __restrict__ scanned,
                              int NB, int NC, int N, int E,
                              int* __restrict__ rowptr, float* __restrict__ dinv,
                              int* __restrict__ colidx) {
    __shared__ int cnt[BSZ], loc[BSZ], woff[BSZ], part[256];
    int b = blockIdx.x;
    int tid = threadIdx.x;
    int ebeg = scanned[b * NC];
    int eend = (b == NB - 1) ? E : scanned[(b + 1) * NC];
    cnt[tid] = 0; cnt[tid + 256] = 0;
    __syncthreads();
    for (int i = ebeg + tid; i < eend; i += 256) {
        int dl = ebuf[i] >> 17;
        atomicAdd(&cnt[dl], 1);
    }
    __syncthreads();
    int a0 = cnt[2 * tid], a1 = cnt[2 * tid + 1];
    part[tid] = a0 + a1;
    __syncthreads();
    for (int off = 1; off < 256; off <<= 1) {
        int v = (tid >= off) ? part[tid - off] : 0;
        __syncthreads();
        part[tid] += v;
        __syncthreads();
    }
    int base = (tid == 0) ? 0 : part[tid - 1];
    loc[2 * tid] = base;
    loc[2 * tid + 1] = base + a0;
    woff[2 * tid] = base;
    woff[2 * tid + 1] = base + a0;
    __syncthreads();
    for (int dl = tid; dl < BSZ; dl += 256) {
        int node = (b << BSH) + dl;
        if (node < N) {
            rowptr[node] = ebeg + loc[dl];
            dinv[node] = 1.0f / sqrtf((float)(cnt[dl] + 1));   // +1 self loop
        }
    }
    __syncthreads();
    for (int i = ebeg + tid; i < eend; i += 256) {
        int p = ebuf[i];
        int dl = p >> 17;
        int s = p & 0x1FFFF;
        int pos = atomicAdd(&woff[dl], 1);
        colidx[ebeg + pos] = s;
    }
}

// ---------------- graph boundaries (batch is sorted) ----------------
__global__ void gbounds_kernel(const int* __restrict__ batch, int N, int G,
                               int* __restrict__ gptr) {
    int b = blockIdx.x * blockDim.x + threadIdx.x;
    if (b > G) return;
    int lo = 0, hi = N;
    while (lo < hi) {
        int mid = (lo + hi) >> 1;
        if (batch[mid] < b) lo = mid + 1; else hi = mid;
    }
    gptr[b] = lo;
}

// ---------------- GEMM (fp32 in) -> fp8 rows; 256-row x 64-col tile, 8x8 micro-tile ----------------
// xs k-major [8][256], ws [8][64]; per k: 4 ds_read_b128 for 64 FMAs (1 B/FMA).
__global__ void gemm_f32_kernel(const float* __restrict__ in, int K, int f4stride,
                                const float* __restrict__ W, int H,
                                const float* __restrict__ dinv,
                                unsigned int* __restrict__ out, int N) {
    __shared__ float xs[8][256];
    __shared__ float ws[8][64];
    int row0 = blockIdx.x * 256;
    int rg = threadIdx.x >> 3;   // 0..31 -> rows rg*8..+7
    int cg = threadIdx.x & 7;    // 0..7  -> cols cg*8..+7
    int rl = threadIdx.x >> 1;   // 0..127 (staging row)
    int h  = threadIdx.x & 1;    // k-half
    int ks = h * 4;
    float acc[8][8];
#pragma unroll
    for (int r = 0; r < 8; r++)
#pragma unroll
        for (int c = 0; c < 8; c++) acc[r][c] = 0.0f;
    const float4* inf4 = (const float4*)in;

    for (int k0 = 0; k0 < K; k0 += 8) {
        // stage ws (512 floats)
        for (int i = threadIdx.x; i < 512; i += 256) {
            int k = i >> 6, c = i & 63;
            ws[k][c] = (k0 + k < K && c < H) ? W[(k0 + k) * H + c] : 0.0f;
        }
        // stage xs (2048 floats, transpose to k-major)
        {
            int row = row0 + rl;
            float4 xv = make_float4(0.f, 0.f, 0.f, 0.f);
            if (row < N) xv = inf4[(size_t)row * f4stride + (k0 >> 2) + h];
            xs[ks + 0][rl] = xv.x; xs[ks + 1][rl] = xv.y;
            xs[ks + 2][rl] = xv.z; xs[ks + 3][rl] = xv.w;
            row = row0 + rl + 128;
            xv = make_float4(0.f, 0.f, 0.f, 0.f);
            if (row < N) xv = inf4[(size_t)row * f4stride + (k0 >> 2) + h];
            xs[ks + 0][rl + 128] = xv.x; xs[ks + 1][rl + 128] = xv.y;
            xs[ks + 2][rl + 128] = xv.z; xs[ks + 3][rl + 128] = xv.w;
        }
        __syncthreads();
#pragma unroll
        for (int k = 0; k < 8; k++) {
            float4 xa = *(const float4*)&xs[k][rg * 8];
            float4 xb = *(const float4*)&xs[k][rg * 8 + 4];
            float4 wa = *(const float4*)&ws[k][cg * 8];
            float4 wb = *(const float4*)&ws[k][cg * 8 + 4];
            float xr[8] = {xa.x, xa.y, xa.z, xa.w, xb.x, xb.y, xb.z, xb.w};
            float wc[8] = {wa.x, wa.y, wa.z, wa.w, wb.x, wb.y, wb.z, wb.w};
#pragma unroll
            for (int r = 0; r < 8; r++)
#pragma unroll
                for (int c = 0; c < 8; c++) acc[r][c] += xr[r] * wc[c];
        }
        __syncthreads();
    }
#pragma unroll
    for (int r = 0; r < 8; r++) {
        int row = row0 + rg * 8 + r;
        if (row < N) {
            float dv = dinv[row];
            uint2 o;
            o.x = pack4_fp8(acc[r][0] * dv, acc[r][1] * dv, acc[r][2] * dv, acc[r][3] * dv);
            o.y = pack4_fp8(acc[r][4] * dv, acc[r][5] * dv, acc[r][6] * dv, acc[r][7] * dv);
            ((uint2*)(out + (size_t)row * 16))[cg] = o;
        }
    }
}

// ---------------- GEMM (bf16 in rows, stride 32 uints) -> fp8 rows; same tiling ----------------
__global__ void gemm_bf16_kernel(const unsigned int* __restrict__ in, int K,
                                 const float* __restrict__ W, int H,
                                 const float* __restrict__ dinv,
                                 unsigned int* __restrict__ out, int N) {
    __shared__ float xs[8][256];
    __shared__ float ws[8][64];
    int row0 = blockIdx.x * 256;
    int rg = threadIdx.x >> 3;
    int cg = threadIdx.x & 7;
    int rl = threadIdx.x >> 1;
    int h  = threadIdx.x & 1;
    int ks = h * 4;
    float acc[8][8];
#pragma unroll
    for (int r = 0; r < 8; r++)
#pragma unroll
        for (int c = 0; c < 8; c++) acc[r][c] = 0.0f;
    const uint2* inu2 = (const uint2*)in;

    for (int k0 = 0; k0 < K; k0 += 8) {
        for (int i = threadIdx.x; i < 512; i += 256) {
            int k = i >> 6, c = i & 63;
            ws[k][c] = (k0 + k < K && c < H) ? W[(k0 + k) * H + c] : 0.0f;
        }
        {
            int row = row0 + rl;
            uint2 xv = make_uint2(0u, 0u);
            if (row < N) xv = inu2[(size_t)row * 16 + (k0 >> 2) + h];
            xs[ks + 0][rl] = bf_lo(xv.x); xs[ks + 1][rl] = bf_hi(xv.x);
            xs[ks + 2][rl] = bf_lo(xv.y); xs[ks + 3][rl] = bf_hi(xv.y);
            row = row0 + rl + 128;
            xv = make_uint2(0u, 0u);
            if (row < N) xv = inu2[(size_t)row * 16 + (k0 >> 2) + h];
            xs[ks + 0][rl + 128] = bf_lo(xv.x); xs[ks + 1][rl + 128] = bf_hi(xv.x);
            xs[ks + 2][rl + 128] = bf_lo(xv.y); xs[ks + 3][rl + 128] = bf_hi(xv.y);
        }
        __syncthreads();
#pragma unroll
        for (int k = 0; k < 8; k++) {
            float4 xa = *(const float4*)&xs[k][rg * 8];
            float4 xb = *(const float4*)&xs[k][rg * 8 + 4];
            float4 wa = *(const float4*)&ws[k][cg * 8];
            float4 wb = *(const float4*)&ws[k][cg * 8 + 4];
            float xr[8] = {xa.x, xa.y, xa.z, xa.w, xb.x, xb.y, xb.z, xb.w};
            float wc[8] = {wa.x, wa.y, wa.z, wa.w, wb.x, wb.y, wb.z, wb.w};
#pragma unroll
            for (int r = 0; r < 8; r++)
#pragma unroll
                for (int c = 0; c < 8; c++) acc[r][c] += xr[r] * wc[c];
        }
        __syncthreads();
    }
#pragma unroll
    for (int r = 0; r < 8; r++) {
        int row = row0 + rg * 8 + r;
        if (row < N) {
            float dv = dinv[row];
            uint2 o;
            o.x = pack4_fp8(acc[r][0] * dv, acc[r][1] * dv, acc[r][2] * dv, acc[r][3] * dv);
            o.y = pack4_fp8(acc[r][4] * dv, acc[r][5] * dv, acc[r][6] * dv, acc[r][7] * dv);
            ((uint2*)(out + (size_t)row * 16))[cg] = o;
        }
    }
}

// ---------------- aggregation over fp8 rows -> bf16 out rows ----------------
__global__ void agg_kernel(const unsigned int* __restrict__ hs, const int* __restrict__ rowptr,
                           const int* __restrict__ colidx, const float* __restrict__ dinv,
                           const float* __restrict__ bias, unsigned int* __restrict__ out, int N) {
    int t = blockIdx.x * blockDim.x + threadIdx.x;
    int node = t >> 4;
    int q = t & 15;
    if (node >= N) return;
    const unsigned int* basq = hs + q;
    unsigned int sv = basq[(size_t)node * 16];   // self loop term
    floatx2 plo = __builtin_amdgcn_cvt_pk_f32_fp8((int)sv, false);
    floatx2 phi = __builtin_amdgcn_cvt_pk_f32_fp8((int)sv, true);
    float a0 = plo[0], a1 = plo[1], a2 = phi[0], a3 = phi[1];
    int beg = rowptr[node], end = rowptr[node + 1];
    int e = beg;
    for (; e + 2 <= end; e += 2) {
        int s0 = colidx[e];
        int s1 = colidx[e + 1];
        unsigned int v0 = basq[(size_t)s0 * 16];
        unsigned int v1 = basq[(size_t)s1 * 16];
        floatx2 l0 = __builtin_amdgcn_cvt_pk_f32_fp8((int)v0, false);
        floatx2 h0 = __builtin_amdgcn_cvt_pk_f32_fp8((int)v0, true);
        floatx2 l1 = __builtin_amdgcn_cvt_pk_f32_fp8((int)v1, false);
        floatx2 h1 = __builtin_amdgcn_cvt_pk_f32_fp8((int)v1, true);
        a0 += l0[0] + l1[0]; a1 += l0[1] + l1[1];
        a2 += h0[0] + h1[0]; a3 += h0[1] + h1[1];
    }
    if (e < end) {
        int s0 = colidx[e];
        unsigned int v0 = basq[(size_t)s0 * 16];
        floatx2 l0 = __builtin_amdgcn_cvt_pk_f32_fp8((int)v0, false);
        floatx2 h0 = __builtin_amdgcn_cvt_pk_f32_fp8((int)v0, true);
        a0 += l0[0]; a1 += l0[1]; a2 += h0[0]; a3 += h0[1];
    }
    float dv = dinv[node];
    int c0 = q * 4;
    float b0 = (c0 + 0 < HH) ? bias[c0 + 0] : 0.0f;
    float b1 = (c0 + 1 < HH) ? bias[c0 + 1] : 0.0f;
    float b2 = (c0 + 2 < HH) ? bias[c0 + 2] : 0.0f;
    float b3 = (c0 + 3 < HH) ? bias[c0 + 3] : 0.0f;
    float r0 = fmaxf(a0 * dv + b0, 0.0f);
    float r1 = fmaxf(a1 * dv + b1, 0.0f);
    float r2 = fmaxf(a2 * dv + b2, 0.0f);
    float r3 = fmaxf(a3 * dv + b3, 0.0f);
    uint2 w;
    if (c0 >= HH) { w.x = 0u; w.y = 0u; }
    else { w.x = f2bf_pair(r0, r1); w.y = f2bf_pair(r2, r3); }
    ((uint2*)out)[(size_t)node * 16 + q] = w;
}

// ---------------- pooling + head over bf16 rows ----------------
__global__ void pool_head_kernel(const unsigned int* __restrict__ h, const int* __restrict__ gptr,
                                 const float* __restrict__ Wl, const float* __restrict__ bl,
                                 float* __restrict__ out, int G) {
    __shared__ float4 red[16][16];    // [sub][q]
    int b = blockIdx.x;
    int t = threadIdx.x;
    int sub = t >> 4, q = t & 15;
    int beg = gptr[b], end = gptr[b + 1];
    const uint2* base = (const uint2*)h;
    float4 acc = make_float4(0.f, 0.f, 0.f, 0.f);
    for (int node = beg + sub; node < end; node += 16) {
        uint2 v = base[(size_t)node * 16 + q];
        acc.x += bf_lo(v.x); acc.y += bf_hi(v.x); acc.z += bf_lo(v.y); acc.w += bf_hi(v.y);
    }
    red[sub][q] = acc;
    __syncthreads();
#pragma unroll
    for (int off = 8; off >= 1; off >>= 1) {
        if (sub < off) {
            float4 a = red[sub][q], c = red[sub + off][q];
            a.x += c.x; a.y += c.y; a.z += c.z; a.w += c.w;
            red[sub][q] = a;
        }
        __syncthreads();
    }
    if (t == 0) {
        const float* g = (const float*)&red[0][0];
        float dot = 0.0f;
        for (int c = 0; c < HH; c++) dot += g[c] * Wl[c];
        float cnt = (float)(end - beg);
        float x = dot / fmaxf(cnt, 1.0f) + bl[0];
        out[b] = 1.0f / (1.0f + expf(-x));
    }
}

extern "C" void kernel_launch(void* const* d_in, const int* in_sizes, int n_in,
                              void* d_out, int out_size, void* d_ws, size_t ws_size,
                              hipStream_t stream) {
    const float* x     = (const float*)d_in[0];
    const int*   ei    = (const int*)d_in[1];
    const int*   batch = (const int*)d_in[2];
    const float* W1    = (const float*)d_in[3];
    const float* b1    = (const float*)d_in[4];
    const float* W2    = (const float*)d_in[5];
    const float* b2    = (const float*)d_in[6];
    const float* Wl    = (const float*)d_in[7];
    const float* bl    = (const float*)d_in[8];
    float* out = (float*)d_out;

    int N = in_sizes[2];
    int E = in_sizes[1] / 2;
    int F = in_sizes[0] / N;       // 136
    int G = out_size;              // 256 graphs

    int NB = (N + BSZ - 1) >> BSH;
    int NC = (E + CH - 1) / CH;

    char* ws = (char*)d_ws;
    size_t off = 0;
    auto alloc = [&](size_t bytes) -> void* {
        void* p = ws + off;
        off += (bytes + 255) & ~(size_t)255;
        return p;
    };
    size_t hsBytes   = (size_t)N * HS;       // fp8 rows (64B)
    size_t bufBytes  = (size_t)N * HS * 2;   // bf16 rows (128B)
    size_t ebufBytes = (size_t)E * 4;
    float*        dinv      = (float*)alloc((size_t)N * 4);
    int*          rowptr    = (int*)alloc((size_t)(N + 1) * 4);
    int*          colidx    = (int*)alloc(ebufBytes);
    unsigned int* hs        = (unsigned int*)alloc(hsBytes > ebufBytes ? hsBytes : ebufBytes);
    unsigned int* buf       = (unsigned int*)alloc(bufBytes);
    int*          gptr      = (int*)alloc((size_t)(G + 1) * 4);
    int*          blockHist = (int*)alloc((size_t)NB * NC * 4);
    int*          scanned   = (int*)alloc((size_t)NB * NC * 4);
    int*          ebuf      = (int*)hs;     // alias: dead before gemm1 writes hs

    // CSR build (by dst), no global atomics
    histA_kernel<<<NC, 256, 0, stream>>>(ei, E, NB, NC, blockHist);
    scanB_kernel<<<1, 1024, 0, stream>>>(blockHist, NB * NC, scanned, rowptr, N, E);
    scatterB_kernel<<<NC, 256, 0, stream>>>(ei, E, NB, NC, scanned, ebuf);
    buildC_kernel<<<NB, 256, 0, stream>>>(ebuf, scanned, NB, NC, N, E, rowptr, dinv, colidx);
    gbounds_kernel<<<2, 256, 0, stream>>>(batch, N, G, gptr);

    int aggBlocks = ((N * 16) + 255) / 256;
    int gemmBlocks = (N + 255) / 256;

    // layer 1
    gemm_f32_kernel<<<gemmBlocks, 256, 0, stream>>>(x, F, F / 4, W1, HH, dinv, hs, N);
    agg_kernel<<<aggBlocks, 256, 0, stream>>>(hs, rowptr, colidx, dinv, b1, buf, N);

    // layer 2
    gemm_bf16_kernel<<<gemmBlocks, 256, 0, stream>>>(buf, 52, W2, HH, dinv, hs, N);
    agg_kernel<<<aggBlocks, 256, 0, stream>>>(hs, rowptr, colidx, dinv, b2, buf, N);

    // pooling + fused head
    pool_head_kernel<<<G, 256, 0, stream>>>(buf, gptr, Wl, bl, out, G);
}

// Round 9
// 350.043 us; speedup vs baseline: 3.3245x; 1.0008x over previous
//
#include <hip/hip_runtime.h>
#include <math.h>

#define HH 50     // hidden features
#define BSH 9     // bucket shift: 512 nodes per bucket
#define BSZ 512
#define CH 16384  // edges per chunk in bucketed CSR build

typedef float floatx2 __attribute__((ext_vector_type(2)));

__device__ __forceinline__ unsigned int f2bf_pair(float f0, float f1) {
    unsigned int u0 = __float_as_uint(f0);
    unsigned int u1 = __float_as_uint(f1);
    u0 = (u0 + 0x7FFFu + ((u0 >> 16) & 1u)) >> 16;   // RNE
    u1 = (u1 + 0x7FFFu + ((u1 >> 16) & 1u)) >> 16;
    return u0 | (u1 << 16);
}
__device__ __forceinline__ float bf_lo(unsigned int p) { return __uint_as_float(p << 16); }
__device__ __forceinline__ float bf_hi(unsigned int p) { return __uint_as_float(p & 0xFFFF0000u); }

// pack 4 floats -> 4x fp8 e4m3 (hardware RNE)
__device__ __forceinline__ unsigned int pack4_fp8(float f0, float f1, float f2, float f3) {
    int r = 0;
    r = __builtin_amdgcn_cvt_pk_fp8_f32(f0, f1, r, false);
    r = __builtin_amdgcn_cvt_pk_fp8_f32(f2, f3, r, true);
    return (unsigned int)r;
}

// ---------------- bucketed CSR build (no global atomics) ----------------
__global__ void histA_kernel(const int* __restrict__ ei, int E, int NB, int NC,
                             int* __restrict__ blockHist) {
    __shared__ int hist[256];
    int c = blockIdx.x;
    int tid = threadIdx.x;
    hist[tid] = 0;
    __syncthreads();
    int beg = c * CH, end = min(E, beg + CH);
    for (int i = beg + tid; i < end; i += 256) {
        int d = ei[(size_t)E + i];
        atomicAdd(&hist[d >> BSH], 1);
    }
    __syncthreads();
    if (tid < NB) blockHist[tid * NC + c] = hist[tid];   // bucket-major
}

__global__ void scanB_kernel(const int* __restrict__ blockHist, int M,
                             int* __restrict__ scanned, int* __restrict__ rowptr,
                             int N, int E) {
    __shared__ int part[1024];
    int t = threadIdx.x;
    int chunk = (M + 1023) >> 10;
    int beg = t * chunk; if (beg > M) beg = M;
    int end = beg + chunk; if (end > M) end = M;
    int s = 0;
    for (int i = beg; i < end; i++) s += blockHist[i];
    part[t] = s;
    __syncthreads();
    for (int off = 1; off < 1024; off <<= 1) {
        int v = (t >= off) ? part[t - off] : 0;
        __syncthreads();
        part[t] += v;
        __syncthreads();
    }
    int run = (t == 0) ? 0 : part[t - 1];
    for (int i = beg; i < end; i++) { scanned[i] = run; run += blockHist[i]; }
    if (t == 0) rowptr[N] = E;
}

__global__ void scatterB_kernel(const int* __restrict__ ei, int E, int NB, int NC,
                                const int* __restrict__ scanned, int* __restrict__ ebuf) {
    __shared__ int offs[256];
    int c = blockIdx.x;
    int tid = threadIdx.x;
    if (tid < NB) offs[tid] = scanned[tid * NC + c];
    __syncthreads();
    int beg = c * CH, end = min(E, beg + CH);
    for (int i = beg + tid; i < end; i += 256) {
        int s = ei[i];
        int d = ei[(size_t)E + i];
        int b = d >> BSH;
        int pos = atomicAdd(&offs[b], 1);
        ebuf[pos] = ((d & (BSZ - 1)) << 17) | s;
    }
}

__global__ void buildC_kernel(const int* __restrict__ ebuf, const int* __restrict__ scanned,
                              int NB, int NC, int N, int E,
                              int* __restrict__ rowptr, float* __restrict__ dinv,
                              int* __restrict__ colidx) {
    __shared__ int cnt[BSZ], loc[BSZ], woff[BSZ], part[256];
    int b = blockIdx.x;
    int tid = threadIdx.x;
    int ebeg = scanned[b * NC];
    int eend = (b == NB - 1) ? E : scanned[(b + 1) * NC];
    cnt[tid] = 0; cnt[tid + 256] = 0;
    __syncthreads();
    for (int i = ebeg + tid; i < eend; i += 256) {
        int dl = ebuf[i] >> 17;
        atomicAdd(&cnt[dl], 1);
    }
    __syncthreads();
    int a0 = cnt[2 * tid], a1 = cnt[2 * tid + 1];
    part[tid] = a0 + a1;
    __syncthreads();
    for (int off = 1; off < 256; off <<= 1) {
        int v = (tid >= off) ? part[tid - off] : 0;
        __syncthreads();
        part[tid] += v;
        __syncthreads();
    }
    int base = (tid == 0) ? 0 : part[tid - 1];
    loc[2 * tid] = base;
    loc[2 * tid + 1] = base + a0;
    woff[2 * tid] = base;
    woff[2 * tid + 1] = base + a0;
    __syncthreads();
    for (int dl = tid; dl < BSZ; dl += 256) {
        int node = (b << BSH) + dl;
        if (node < N) {
            rowptr[node] = ebeg + loc[dl];
            dinv[node] = 1.0f / sqrtf((float)(cnt[dl] + 1));   // +1 self loop
        }
    }
    __syncthreads();
    for (int i = ebeg + tid; i < eend; i += 256) {
        int p = ebuf[i];
        int dl = p >> 17;
        int s = p & 0x1FFFF;
        int pos = atomicAdd(&woff[dl], 1);
        colidx[ebeg + pos] = s;
    }
}

// ---------------- GEMM (fp32 in) -> fp8 half-rows; 256x64 tile, 8x8 micro-tile ----------------
__global__ void gemm_f32_kernel(const float* __restrict__ in, int K, int f4stride,
                                const float* __restrict__ W, int H,
                                const float* __restrict__ dinv,
                                unsigned int* __restrict__ hsA,
                                unsigned int* __restrict__ hsB, int N) {
    __shared__ float xs[8][256];
    __shared__ float ws[8][64];
    int row0 = blockIdx.x * 256;
    int rg = threadIdx.x >> 3;   // 0..31 -> rows rg*8..+7
    int cg = threadIdx.x & 7;    // 0..7  -> cols cg*8..+7
    int rl = threadIdx.x >> 1;   // 0..127 (staging row)
    int h  = threadIdx.x & 1;    // k-half
    int ks = h * 4;
    float acc[8][8];
#pragma unroll
    for (int r = 0; r < 8; r++)
#pragma unroll
        for (int c = 0; c < 8; c++) acc[r][c] = 0.0f;
    const float4* inf4 = (const float4*)in;

    for (int k0 = 0; k0 < K; k0 += 8) {
        for (int i = threadIdx.x; i < 512; i += 256) {
            int k = i >> 6, c = i & 63;
            ws[k][c] = (k0 + k < K && c < H) ? W[(k0 + k) * H + c] : 0.0f;
        }
        {
            int row = row0 + rl;
            float4 xv = make_float4(0.f, 0.f, 0.f, 0.f);
            if (row < N) xv = inf4[(size_t)row * f4stride + (k0 >> 2) + h];
            xs[ks + 0][rl] = xv.x; xs[ks + 1][rl] = xv.y;
            xs[ks + 2][rl] = xv.z; xs[ks + 3][rl] = xv.w;
            row = row0 + rl + 128;
            xv = make_float4(0.f, 0.f, 0.f, 0.f);
            if (row < N) xv = inf4[(size_t)row * f4stride + (k0 >> 2) + h];
            xs[ks + 0][rl + 128] = xv.x; xs[ks + 1][rl + 128] = xv.y;
            xs[ks + 2][rl + 128] = xv.z; xs[ks + 3][rl + 128] = xv.w;
        }
        __syncthreads();
#pragma unroll
        for (int k = 0; k < 8; k++) {
            float4 xa = *(const float4*)&xs[k][rg * 8];
            float4 xb = *(const float4*)&xs[k][rg * 8 + 4];
            float4 wa = *(const float4*)&ws[k][cg * 8];
            float4 wb = *(const float4*)&ws[k][cg * 8 + 4];
            float xr[8] = {xa.x, xa.y, xa.z, xa.w, xb.x, xb.y, xb.z, xb.w};
            float wc[8] = {wa.x, wa.y, wa.z, wa.w, wb.x, wb.y, wb.z, wb.w};
#pragma unroll
            for (int r = 0; r < 8; r++)
#pragma unroll
                for (int c = 0; c < 8; c++) acc[r][c] += xr[r] * wc[c];
        }
        __syncthreads();
    }
#pragma unroll
    for (int r = 0; r < 8; r++) {
        int row = row0 + rg * 8 + r;
        if (row < N) {
            float dv = dinv[row];
            uint2 o;
            o.x = pack4_fp8(acc[r][0] * dv, acc[r][1] * dv, acc[r][2] * dv, acc[r][3] * dv);
            o.y = pack4_fp8(acc[r][4] * dv, acc[r][5] * dv, acc[r][6] * dv, acc[r][7] * dv);
            if (cg < 4) ((uint2*)(hsA + (size_t)row * 8))[cg] = o;
            else        ((uint2*)(hsB + (size_t)row * 8))[cg - 4] = o;
        }
    }
}

// ---------------- GEMM (bf16 in rows, stride 32 uints) -> fp8 half-rows ----------------
__global__ void gemm_bf16_kernel(const unsigned int* __restrict__ in, int K,
                                 const float* __restrict__ W, int H,
                                 const float* __restrict__ dinv,
                                 unsigned int* __restrict__ hsA,
                                 unsigned int* __restrict__ hsB, int N) {
    __shared__ float xs[8][256];
    __shared__ float ws[8][64];
    int row0 = blockIdx.x * 256;
    int rg = threadIdx.x >> 3;
    int cg = threadIdx.x & 7;
    int rl = threadIdx.x >> 1;
    int h  = threadIdx.x & 1;
    int ks = h * 4;
    float acc[8][8];
#pragma unroll
    for (int r = 0; r < 8; r++)
#pragma unroll
        for (int c = 0; c < 8; c++) acc[r][c] = 0.0f;
    const uint2* inu2 = (const uint2*)in;

    for (int k0 = 0; k0 < K; k0 += 8) {
        for (int i = threadIdx.x; i < 512; i += 256) {
            int k = i >> 6, c = i & 63;
            ws[k][c] = (k0 + k < K && c < H) ? W[(k0 + k) * H + c] : 0.0f;
        }
        {
            int row = row0 + rl;
            uint2 xv = make_uint2(0u, 0u);
            if (row < N) xv = inu2[(size_t)row * 16 + (k0 >> 2) + h];
            xs[ks + 0][rl] = bf_lo(xv.x); xs[ks + 1][rl] = bf_hi(xv.x);
            xs[ks + 2][rl] = bf_lo(xv.y); xs[ks + 3][rl] = bf_hi(xv.y);
            row = row0 + rl + 128;
            xv = make_uint2(0u, 0u);
            if (row < N) xv = inu2[(size_t)row * 16 + (k0 >> 2) + h];
            xs[ks + 0][rl + 128] = bf_lo(xv.x); xs[ks + 1][rl + 128] = bf_hi(xv.x);
            xs[ks + 2][rl + 128] = bf_lo(xv.y); xs[ks + 3][rl + 128] = bf_hi(xv.y);
        }
        __syncthreads();
#pragma unroll
        for (int k = 0; k < 8; k++) {
            float4 xa = *(const float4*)&xs[k][rg * 8];
            float4 xb = *(const float4*)&xs[k][rg * 8 + 4];
            float4 wa = *(const float4*)&ws[k][cg * 8];
            float4 wb = *(const float4*)&ws[k][cg * 8 + 4];
            float xr[8] = {xa.x, xa.y, xa.z, xa.w, xb.x, xb.y, xb.z, xb.w};
            float wc[8] = {wa.x, wa.y, wa.z, wa.w, wb.x, wb.y, wb.z, wb.w};
#pragma unroll
            for (int r = 0; r < 8; r++)
#pragma unroll
                for (int c = 0; c < 8; c++) acc[r][c] += xr[r] * wc[c];
        }
        __syncthreads();
    }
#pragma unroll
    for (int r = 0; r < 8; r++) {
        int row = row0 + rg * 8 + r;
        if (row < N) {
            float dv = dinv[row];
            uint2 o;
            o.x = pack4_fp8(acc[r][0] * dv, acc[r][1] * dv, acc[r][2] * dv, acc[r][3] * dv);
            o.y = pack4_fp8(acc[r][4] * dv, acc[r][5] * dv, acc[r][6] * dv, acc[r][7] * dv);
            if (cg < 4) ((uint2*)(hsA + (size_t)row * 8))[cg] = o;
            else        ((uint2*)(hsB + (size_t)row * 8))[cg - 4] = o;
        }
    }
}

// ---------------- aggregation over one fp8 half (32B rows, L2-resident) ----------------
// thread t -> node t>>3, lane q=t&7 covers cols [cbase+4q, cbase+4q+4)
__global__ void agg_half_kernel(const unsigned int* __restrict__ hsh,
                                const int* __restrict__ rowptr, const int* __restrict__ colidx,
                                const float* __restrict__ dinv, const float* __restrict__ bias,
                                int cbase, unsigned int* __restrict__ outbuf, int N) {
    int t = blockIdx.x * blockDim.x + threadIdx.x;
    int node = t >> 3;
    int q = t & 7;
    if (node >= N) return;
    const unsigned int* basq = hsh + q;
    unsigned int sv = basq[(size_t)node * 8];   // self loop term
    floatx2 plo = __builtin_amdgcn_cvt_pk_f32_fp8((int)sv, false);
    floatx2 phi = __builtin_amdgcn_cvt_pk_f32_fp8((int)sv, true);
    float a0 = plo[0], a1 = plo[1], a2 = phi[0], a3 = phi[1];
    int beg = rowptr[node], end = rowptr[node + 1];
    int e = beg;
    for (; e + 4 <= end; e += 4) {
        int s0 = colidx[e], s1 = colidx[e + 1], s2 = colidx[e + 2], s3 = colidx[e + 3];
        unsigned int v0 = basq[(size_t)s0 * 8];
        unsigned int v1 = basq[(size_t)s1 * 8];
        unsigned int v2 = basq[(size_t)s2 * 8];
        unsigned int v3 = basq[(size_t)s3 * 8];
        floatx2 l0 = __builtin_amdgcn_cvt_pk_f32_fp8((int)v0, false);
        floatx2 h0 = __builtin_amdgcn_cvt_pk_f32_fp8((int)v0, true);
        floatx2 l1 = __builtin_amdgcn_cvt_pk_f32_fp8((int)v1, false);
        floatx2 h1 = __builtin_amdgcn_cvt_pk_f32_fp8((int)v1, true);
        floatx2 l2 = __builtin_amdgcn_cvt_pk_f32_fp8((int)v2, false);
        floatx2 h2 = __builtin_amdgcn_cvt_pk_f32_fp8((int)v2, true);
        floatx2 l3 = __builtin_amdgcn_cvt_pk_f32_fp8((int)v3, false);
        floatx2 h3 = __builtin_amdgcn_cvt_pk_f32_fp8((int)v3, true);
        a0 += (l0[0] + l1[0]) + (l2[0] + l3[0]);
        a1 += (l0[1] + l1[1]) + (l2[1] + l3[1]);
        a2 += (h0[0] + h1[0]) + (h2[0] + h3[0]);
        a3 += (h0[1] + h1[1]) + (h2[1] + h3[1]);
    }
    for (; e < end; e++) {
        int s0 = colidx[e];
        unsigned int v0 = basq[(size_t)s0 * 8];
        floatx2 l0 = __builtin_amdgcn_cvt_pk_f32_fp8((int)v0, false);
        floatx2 h0 = __builtin_amdgcn_cvt_pk_f32_fp8((int)v0, true);
        a0 += l0[0]; a1 += l0[1]; a2 += h0[0]; a3 += h0[1];
    }
    float dv = dinv[node];
    int c0 = cbase + q * 4;
    float b0 = (c0 + 0 < HH) ? bias[c0 + 0] : 0.0f;
    float b1 = (c0 + 1 < HH) ? bias[c0 + 1] : 0.0f;
    float b2 = (c0 + 2 < HH) ? bias[c0 + 2] : 0.0f;
    float b3 = (c0 + 3 < HH) ? bias[c0 + 3] : 0.0f;
    float r0 = fmaxf(a0 * dv + b0, 0.0f);
    float r1 = fmaxf(a1 * dv + b1, 0.0f);
    float r2 = fmaxf(a2 * dv + b2, 0.0f);
    float r3 = fmaxf(a3 * dv + b3, 0.0f);
    uint2 w;
    if (c0 >= HH) { w.x = 0u; w.y = 0u; }
    else { w.x = f2bf_pair(r0, r1); w.y = f2bf_pair(r2, r3); }
    ((uint2*)outbuf)[(size_t)node * 16 + (cbase >> 2) + q] = w;
}

// ---------------- pooling + head over bf16 rows (bounds searched inline) ----------------
__global__ void pool_head_kernel(const unsigned int* __restrict__ h,
                                 const int* __restrict__ batch, int N,
                                 const float* __restrict__ Wl, const float* __restrict__ bl,
                                 float* __restrict__ out, int G) {
    __shared__ float4 red[16][16];    // [sub][q]
    int b = blockIdx.x;
    int t = threadIdx.x;
    int sub = t >> 4, q = t & 15;
    // lower_bound(batch, b) and lower_bound(batch, b+1)
    int beg, end;
    {
        int lo = 0, hi = N;
        while (lo < hi) { int mid = (lo + hi) >> 1; if (batch[mid] < b) lo = mid + 1; else hi = mid; }
        beg = lo;
        lo = 0; hi = N;
        while (lo < hi) { int mid = (lo + hi) >> 1; if (batch[mid] < b + 1) lo = mid + 1; else hi = mid; }
        end = lo;
    }
    const uint2* base = (const uint2*)h;
    float4 acc = make_float4(0.f, 0.f, 0.f, 0.f);
    for (int node = beg + sub; node < end; node += 16) {
        uint2 v = base[(size_t)node * 16 + q];
        acc.x += bf_lo(v.x); acc.y += bf_hi(v.x); acc.z += bf_lo(v.y); acc.w += bf_hi(v.y);
    }
    red[sub][q] = acc;
    __syncthreads();
#pragma unroll
    for (int off = 8; off >= 1; off >>= 1) {
        if (sub < off) {
            float4 a = red[sub][q], c = red[sub + off][q];
            a.x += c.x; a.y += c.y; a.z += c.z; a.w += c.w;
            red[sub][q] = a;
        }
        __syncthreads();
    }
    if (t == 0) {
        const float* g = (const float*)&red[0][0];
        float dot = 0.0f;
        for (int c = 0; c < HH; c++) dot += g[c] * Wl[c];
        float cnt = (float)(end - beg);
        float x = dot / fmaxf(cnt, 1.0f) + bl[0];
        out[b] = 1.0f / (1.0f + expf(-x));
    }
}

extern "C" void kernel_launch(void* const* d_in, const int* in_sizes, int n_in,
                              void* d_out, int out_size, void* d_ws, size_t ws_size,
                              hipStream_t stream) {
    const float* x     = (const float*)d_in[0];
    const int*   ei    = (const int*)d_in[1];
    const int*   batch = (const int*)d_in[2];
    const float* W1    = (const float*)d_in[3];
    const float* b1    = (const float*)d_in[4];
    const float* W2    = (const float*)d_in[5];
    const float* b2    = (const float*)d_in[6];
    const float* Wl    = (const float*)d_in[7];
    const float* bl    = (const float*)d_in[8];
    float* out = (float*)d_out;

    int N = in_sizes[2];
    int E = in_sizes[1] / 2;
    int F = in_sizes[0] / N;       // 136
    int G = out_size;              // 256 graphs

    int NB = (N + BSZ - 1) >> BSH;
    int NC = (E + CH - 1) / CH;

    char* ws = (char*)d_ws;
    size_t off = 0;
    auto alloc = [&](size_t bytes) -> void* {
        void* p = ws + off;
        off += (bytes + 255) & ~(size_t)255;
        return p;
    };
    size_t halfBytes = (size_t)N * 32;       // fp8 half rows (32B)
    size_t bufBytes  = (size_t)N * 128;      // bf16 rows (128B)
    size_t ebufBytes = (size_t)E * 4;
    float*        dinv      = (float*)alloc((size_t)N * 4);
    int*          rowptr    = (int*)alloc((size_t)(N + 1) * 4);
    int*          colidx    = (int*)alloc(ebufBytes);
    unsigned int* hsA       = (unsigned int*)alloc(halfBytes);
    unsigned int* hsB       = (unsigned int*)alloc(halfBytes);
    unsigned int* buf       = (unsigned int*)alloc(bufBytes > ebufBytes ? bufBytes : ebufBytes);
    int*          blockHist = (int*)alloc((size_t)NB * NC * 4);
    int*          scanned   = (int*)alloc((size_t)NB * NC * 4);
    int*          ebuf      = (int*)buf;    // alias: dead before first agg writes buf

    // CSR build (by dst), no global atomics
    histA_kernel<<<NC, 256, 0, stream>>>(ei, E, NB, NC, blockHist);
    scanB_kernel<<<1, 1024, 0, stream>>>(blockHist, NB * NC, scanned, rowptr, N, E);
    scatterB_kernel<<<NC, 256, 0, stream>>>(ei, E, NB, NC, scanned, ebuf);
    buildC_kernel<<<NB, 256, 0, stream>>>(ebuf, scanned, NB, NC, N, E, rowptr, dinv, colidx);

    int aggBlocks = ((N * 8) + 255) / 256;
    int gemmBlocks = (N + 255) / 256;

    // layer 1
    gemm_f32_kernel<<<gemmBlocks, 256, 0, stream>>>(x, F, F / 4, W1, HH, dinv, hsA, hsB, N);
    agg_half_kernel<<<aggBlocks, 256, 0, stream>>>(hsA, rowptr, colidx, dinv, b1, 0,  buf, N);
    agg_half_kernel<<<aggBlocks, 256, 0, stream>>>(hsB, rowptr, colidx, dinv, b1, 32, buf, N);

    // layer 2 (K=50 real rows of W2; buf pad cols are exact zeros)
    gemm_bf16_kernel<<<gemmBlocks, 256, 0, stream>>>(buf, 50, W2, HH, dinv, hsA, hsB, N);
    agg_half_kernel<<<aggBlocks, 256, 0, stream>>>(hsA, rowptr, colidx, dinv, b2, 0,  buf, N);
    agg_half_kernel<<<aggBlocks, 256, 0, stream>>>(hsB, rowptr, colidx, dinv, b2, 32, buf, N);

    // pooling + fused head
    pool_head_kernel<<<G, 256, 0, stream>>>(buf, batch, N, Wl, bl, out, G);
}